// Round 10
// baseline (882.785 us; speedup 1.0000x reference)
//
#include <hip/hip_runtime.h>
#include <hip/hip_fp16.h>

typedef unsigned short u16;
typedef float f32x4 __attribute__((ext_vector_type(4)));
typedef _Float16 half8 __attribute__((ext_vector_type(8)));
typedef unsigned short u16x4 __attribute__((ext_vector_type(4)));

#define CDIM 768
#define NP 1024
#define NB 32

static constexpr size_t CHW = (size_t)NB * CDIM * NP;  // 25,165,824

// workspace layout (bytes)
static constexpr size_t XT_OFF  = 0;                         // f16 [b][p][c]; later reused as aoT f16
static constexpr size_t HS_OFF  = CHW * 2;                   // f16 hs11, hs111
static constexpr size_t WHI_OFF = HS_OFF + CHW * 4;          // f16 weights

__device__ __forceinline__ u16 f16bits(float f) {
  return __half_as_ushort(__float2half_rn(f));
}
__device__ __forceinline__ float f16tof(u16 b) {
  __half_raw hr; hr.x = b; return __half2float(__half(hr));
}

typedef __attribute__((address_space(1))) void gv_t;
typedef __attribute__((address_space(3))) void lv_t;
__device__ __forceinline__ void gload_lds16(const void* g, void* l) {
  __builtin_amdgcn_global_load_lds((gv_t*)g, (lv_t*)l, 16, 0, 0);
}

// ---------------- cast W (fp32 -> f16) ----------------
__global__ __launch_bounds__(256) void cast_w_k(const float* __restrict__ W,
                                                u16* __restrict__ hi) {
  int i = blockIdx.x * 256 + threadIdx.x;
  float4 v = ((const float4*)W)[i];
  u16x4 h4 = {f16bits(v.x), f16bits(v.y), f16bits(v.z), f16bits(v.w)};
  ((u16x4*)hi)[i] = h4;
}

// ---------------- transpose + f16 cast: src fp32 [b][c][p] -> dst f16 [b][p][c] ----------------
__global__ __launch_bounds__(256) void transpose_f16_k(const float* __restrict__ src,
                                                       u16* __restrict__ dxt) {
  __shared__ float tle[32][33];
  const int b = blockIdx.z, c0 = blockIdx.y * 32, p0 = blockIdx.x * 32;
  const int tid = threadIdx.x;
  const int lr = tid >> 5, lc = tid & 31;
  const float* s = src + ((size_t)b * CDIM + c0) * NP + p0;
#pragma unroll
  for (int it = 0; it < 4; ++it) {
    int c = it * 8 + lr;
    tle[c][lc] = s[(size_t)c * NP + lc];
  }
  __syncthreads();
#pragma unroll
  for (int it = 0; it < 4; ++it) {
    int p = it * 8 + lr;
    float v = tle[lc][p];
    size_t off = ((size_t)b * NP + p0 + p) * CDIM + c0 + lc;
    dxt[off] = f16bits(v);
  }
}

// ---------------- spatial permutations ----------------
__device__ __forceinline__ int sigma_fn(int mode, int z, int t, int p) {
  if (t == 0 || mode == 1) return p;
  int i = p >> 5, j = p & 31;
  if (z == 0) {
    if (t == 1) return (j << 5) | (31 - i);
    if (t == 2) return ((31 - i) << 5) | (31 - j);
    return ((31 - j) << 5) | i;
  } else {
    int ib = i & 16, jb = j & 16, il = i & 15, jl = j & 15;
    if (t == 1) return ((ib | jl) << 5) | (jb | (15 - il));
    if (t == 2) return ((ib | (15 - il)) << 5) | (jb | (15 - jl));
    return ((ib | (15 - jl)) << 5) | (jb | il);
  }
}

// ---------------- 16-wave 256x256 multi-term f16 GEMM ----------------
// 1024 threads = 16 waves (4M x 4N), wave tile 64x64, BK=32.
// 3 LDS buffers x 32KB: A [0,8192) u16 [256 rows][4 chunks of 8], 64B stride,
// phys = logical ^ ((row>>1)&3) (r7-proven 0-conflict); B [8192,16384) same. +bias.
// Depth-2 prefetch, counted vmcnt(2)/step (2 loads/thread/step), 1 barrier/step.
// 4 waves/SIMD on one block (96KB LDS) -> stalls covered by wave-level overlap.
template <int OUTF16, int NTERMS>
__global__ __launch_bounds__(1024, 4) void gemm_q(
    const u16* __restrict__ Whi,
    const u16* __restrict__ Bx,
    const float* __restrict__ bias, void* __restrict__ dst,
    int wselBase, int mode) {
  extern __shared__ u16 lds[];  // 3 x 16384 u16 + NTERMS*256 f32 bias
  const int tid = threadIdx.x;
  const int lane = tid & 63;
  const int w = tid >> 6;
  const int wm = w >> 2, wn = w & 3;
  const int z = blockIdx.z;
  const int b = blockIdx.x >> 2;
  const int p0 = (blockIdx.x & 3) << 8;
  const int o0 = blockIdx.y << 8;
  const int l15 = lane & 15, l4 = lane >> 4;
  float* blds = (float*)(lds + 49152);

  const int NSTEP = NTERMS * 24;

  // LDS read bases (u16 units); frag m/n: +m*512 (16 rows); XOR invariant under +16 rows
  const int rA = wm * 64 + l15;
  const int baseA = rA * 32 + (l4 ^ ((rA >> 1) & 3)) * 8;
  const int rB = wn * 64 + l15;
  const int baseB = 8192 + rB * 32 + (l4 ^ ((rB >> 1) & 3)) * 8;

  // staging decode: slot tid -> row = tid>>2 (0..255), phys chunk = tid&3,
  // logical chunk = phys ^ ((row>>1)&3); dest linear tid*16B (gload_lds lane rule)
  const int srow = tid >> 2;
  const int scof = ((tid & 3) ^ ((srow >> 1) & 3)) * 8;
  const int adst = tid * 8;
  const int bdst = 8192 + tid * 8;

  const u16* aptr;
  const u16* bptr;
  int nsk = 0, nst = 0;
  auto setPtrs = [&](int term) {
    int wsel = wselBase + z * 4 + term;
    aptr = Whi + ((size_t)wsel * CDIM + o0 + srow) * CDIM + scof;
    int srw = sigma_fn(mode, z, term, p0 + srow);
    bptr = Bx + ((size_t)b * NP + srw) * CDIM + scof;
  };
  auto stageTo = [&](int buf) {
    u16* lw = lds + buf * 16384;
    gload_lds16(aptr, lw + adst);
    gload_lds16(bptr, lw + bdst);
    aptr += 32; bptr += 32;
    ++nsk;
  };

  // bias -> LDS (global loads drain before staging; ds_write covered by in-loop lgkm waits)
  for (int i = tid; i < NTERMS * 256; i += 1024)
    blds[i] = bias[(size_t)(wselBase + z * 4 + (i >> 8)) * CDIM + o0 + (i & 255)];

  f32x4 acc[4][4], racc[4][4];
#pragma unroll
  for (int m = 0; m < 4; ++m)
#pragma unroll
    for (int n = 0; n < 4; ++n) {
      acc[m][n] = (f32x4){0.f, 0.f, 0.f, 0.f};
      racc[m][n] = (f32x4){0.f, 0.f, 0.f, 0.f};
    }

  // prologue: stage steps 0,1 into bufs 0,1
  setPtrs(0);
  stageTo(0);
  stageTo(1);

  int cur = 0, wb = 2;
  int ckk = 0, cterm = 0;

  for (int s = 0; s < NSTEP; ++s) {
    if (s + 1 < NSTEP) {
      asm volatile("s_waitcnt vmcnt(2)" ::: "memory");
    } else {
      asm volatile("s_waitcnt vmcnt(0)" ::: "memory");
    }
    __builtin_amdgcn_s_barrier();
    asm volatile("" ::: "memory");

    const u16* la = lds + cur * 16384;

    half8 ah[4], bb[4];
#pragma unroll
    for (int m = 0; m < 4; ++m) ah[m] = *(const half8*)(la + baseA + m * 512);
#pragma unroll
    for (int n = 0; n < 4; ++n) bb[n] = *(const half8*)(la + baseB + n * 512);

    if (s + 2 < NSTEP) {
      if (nsk == 24) { ++nst; nsk = 0; setPtrs(nst); }
      stageTo(wb);
    }

    asm volatile("s_waitcnt lgkmcnt(0)" ::: "memory");
    __builtin_amdgcn_s_setprio(1);
#pragma unroll
    for (int m = 0; m < 4; ++m)
#pragma unroll
      for (int n = 0; n < 4; ++n)
        acc[m][n] = __builtin_amdgcn_mfma_f32_16x16x32_f16(ah[m], bb[n], acc[m][n], 0, 0, 0);
    __builtin_amdgcn_s_setprio(0);

    if (ckk == 23) {  // term boundary: relu(acc + bias) -> racc, reset acc
#pragma unroll
      for (int m = 0; m < 4; ++m) {
        float4 bv = *(const float4*)&blds[cterm * 256 + wm * 64 + m * 16 + l4 * 4];
        float bvf[4] = {bv.x, bv.y, bv.z, bv.w};
#pragma unroll
        for (int n = 0; n < 4; ++n)
#pragma unroll
          for (int r = 0; r < 4; ++r) {
            racc[m][n][r] += fmaxf(0.f, acc[m][n][r] + bvf[r]);
            acc[m][n][r] = 0.f;
          }
      }
    }
    cur = cur == 2 ? 0 : cur + 1;
    wb = wb == 2 ? 0 : wb + 1;
    ++ckk; if (ckk == 24) { ckk = 0; ++cterm; }
  }

  // C write: row = o0+wm*64+m*16+l4*4+r, col = p0+wn*64+n*16+l15
#pragma unroll
  for (int m = 0; m < 4; ++m) {
    int rowb = o0 + wm * 64 + m * 16 + l4 * 4;
#pragma unroll
    for (int n = 0; n < 4; ++n) {
      int col = p0 + wn * 64 + n * 16 + l15;
      size_t base = ((size_t)b * CDIM + rowb) * NP + col;
      if (OUTF16) {
        u16* dp = (u16*)dst + (size_t)z * CHW + base;
#pragma unroll
        for (int r = 0; r < 4; ++r) dp[(size_t)r * NP] = f16bits(racc[m][n][r]);
      } else {
        float* dp = (float*)dst + (size_t)z * CHW + base;
#pragma unroll
        for (int r = 0; r < 4; ++r) dp[(size_t)r * NP] = racc[m][n][r];
      }
    }
  }
}

// ---------------- per-(b,c) 32x32 attention, f16 in, fused transposed-f16 output ----------------
__global__ __launch_bounds__(256) void attn_f_k(const u16* __restrict__ hs, u16* __restrict__ aoT) {
  __shared__ float q[4][1056];   // pitch 33
  __shared__ float kk[4][1056];
  const int tid = threadIdx.x, w = tid >> 6, lane = tid & 63;
  const int pair0 = blockIdx.x * 4;
  const int b = pair0 / CDIM;
  const int c0 = pair0 % CDIM;
#pragma unroll
  for (int it = 0; it < 8; ++it) {
    int d4 = it * 256 + tid;
    int pr = d4 >> 9;
    int mat = (d4 >> 8) & 1;
    int off4 = d4 & 255;
    ushort4 hv = *(const ushort4*)&hs[(size_t)mat * CHW + (size_t)(pair0 + pr) * NP + off4 * 4];
    float* dl = mat ? kk[pr] : q[pr];
    int off = off4 * 4;
    int base = (off >> 5) * 33 + (off & 31);
    dl[base] = f16tof(hv.x); dl[base + 1] = f16tof(hv.y);
    dl[base + 2] = f16tof(hv.z); dl[base + 3] = f16tof(hv.w);
  }
  __syncthreads();
  const int i = lane & 31, half = lane >> 5, jb = half * 16;
  const float* Q = q[w];
  const float* K = kk[w];
  float qr[32];
#pragma unroll
  for (int tt = 0; tt < 32; ++tt) qr[tt] = Q[i * 33 + tt];
  float a[16];
#pragma unroll
  for (int j = 0; j < 16; ++j) {
    float s = 0.f;
#pragma unroll
    for (int tt = 0; tt < 32; ++tt) s = fmaf(qr[tt], K[tt * 33 + jb + j], s);
    a[j] = s;
  }
  float mx = a[0];
#pragma unroll
  for (int j = 1; j < 16; ++j) mx = fmaxf(mx, a[j]);
  mx = fmaxf(mx, __shfl_xor(mx, 32));
  float ssum = 0.f;
#pragma unroll
  for (int j = 0; j < 16; ++j) { a[j] = expf(a[j] - mx); ssum += a[j]; }
  ssum += __shfl_xor(ssum, 32);
  float inv = 1.f / ssum;
#pragma unroll
  for (int j = 0; j < 16; ++j) a[j] *= inv;
#pragma unroll
  for (int h = 0; h < 32; ++h) {
    float o = 0.f;
#pragma unroll
    for (int j = 0; j < 16; ++j) o = fmaf(a[j], Q[(jb + j) * 33 + h], o);
    o += __shfl_xor(o, 32);
    if (half == (h >> 4)) kk[w][i * 33 + h] = o;
  }
  __syncthreads();
#pragma unroll
  for (int it = 0; it < 4; ++it) {
    int p = it * 256 + tid;
    int base = (p >> 5) * 33 + (p & 31);
    ushort4 v;
    v.x = f16bits(kk[0][base]);
    v.y = f16bits(kk[1][base]);
    v.z = f16bits(kk[2][base]);
    v.w = f16bits(kk[3][base]);
    *(ushort4*)&aoT[((size_t)b * NP + p) * CDIM + c0] = v;
  }
}

extern "C" void kernel_launch(void* const* d_in, const int* in_sizes, int n_in,
                              void* d_out, int out_size, void* d_ws, size_t ws_size,
                              hipStream_t stream) {
  (void)in_sizes; (void)n_in; (void)out_size; (void)ws_size;
  const float* x = (const float*)d_in[0];
  const float* Ws = (const float*)d_in[1];
  const float* bs = (const float*)d_in[2];
  float* out = (float*)d_out;
  char* ws = (char*)d_ws;

  u16* XT  = (u16*)(ws + XT_OFF);
  u16* hs  = (u16*)(ws + HS_OFF);    // f16 hs11 (z0), hs111 (z1)
  u16* Whi = (u16*)(ws + WHI_OFF);
  u16* aoT = (u16*)(ws + XT_OFF);    // aliases XT (dead after stage-1)

  cast_w_k<<<5184, 256, 0, stream>>>(Ws, Whi);
  transpose_f16_k<<<dim3(32, 24, 32), 256, 0, stream>>>(x, XT);
  // stage-1: hs11 (z=0, W0..3) and hs111 (z=1, W4..7); 256x256 tiles, f16 out
  gemm_q<1, 4><<<dim3(128, 3, 2), 1024, 102400, stream>>>(Whi, XT, bs, (void*)hs, 0, 0);
  attn_f_k<<<6144, 256, 0, stream>>>(hs, aoT);
  // final conv: relu(W8 @ attout + b8) -> d_out (fp32)
  gemm_q<0, 1><<<dim3(128, 3, 1), 1024, 99328, stream>>>(Whi, aoT, bs, (void*)out, 8, 1);
}

// Round 11
// 508.485 us; speedup vs baseline: 1.7361x; 1.7361x over previous
//
#include <hip/hip_runtime.h>
#include <hip/hip_fp16.h>

typedef unsigned short u16;
typedef float f32x4 __attribute__((ext_vector_type(4)));
typedef _Float16 half8 __attribute__((ext_vector_type(8)));
typedef unsigned short u16x4 __attribute__((ext_vector_type(4)));

#define CDIM 768
#define NP 1024
#define NB 32

static constexpr size_t CHW = (size_t)NB * CDIM * NP;  // 25,165,824

// workspace layout (bytes)
static constexpr size_t XT_OFF  = 0;                         // f16 [b][p][c]; later reused as aoT f16
static constexpr size_t HS_OFF  = CHW * 2;                   // f16 hs11, hs111
static constexpr size_t WHI_OFF = HS_OFF + CHW * 4;          // f16 weights

__device__ __forceinline__ u16 f16bits(float f) {
  return __half_as_ushort(__float2half_rn(f));
}
__device__ __forceinline__ float f16tof(u16 b) {
  __half_raw hr; hr.x = b; return __half2float(__half(hr));
}

typedef __attribute__((address_space(1))) void gv_t;
typedef __attribute__((address_space(3))) void lv_t;
__device__ __forceinline__ void gload_lds16(const void* g, void* l) {
  __builtin_amdgcn_global_load_lds((gv_t*)g, (lv_t*)l, 16, 0, 0);
}

// ---------------- cast W (fp32 -> f16) ----------------
__global__ __launch_bounds__(256) void cast_w_k(const float* __restrict__ W,
                                                u16* __restrict__ hi) {
  int i = blockIdx.x * 256 + threadIdx.x;
  float4 v = ((const float4*)W)[i];
  u16x4 h4 = {f16bits(v.x), f16bits(v.y), f16bits(v.z), f16bits(v.w)};
  ((u16x4*)hi)[i] = h4;
}

// ---------------- transpose + f16 cast: src fp32 [b][c][p] -> dst f16 [b][p][c] ----------------
__global__ __launch_bounds__(256) void transpose_f16_k(const float* __restrict__ src,
                                                       u16* __restrict__ dxt) {
  __shared__ float tle[32][33];
  const int b = blockIdx.z, c0 = blockIdx.y * 32, p0 = blockIdx.x * 32;
  const int tid = threadIdx.x;
  const int lr = tid >> 5, lc = tid & 31;
  const float* s = src + ((size_t)b * CDIM + c0) * NP + p0;
#pragma unroll
  for (int it = 0; it < 4; ++it) {
    int c = it * 8 + lr;
    tle[c][lc] = s[(size_t)c * NP + lc];
  }
  __syncthreads();
#pragma unroll
  for (int it = 0; it < 4; ++it) {
    int p = it * 8 + lr;
    float v = tle[lc][p];
    size_t off = ((size_t)b * NP + p0 + p) * CDIM + c0 + lc;
    dxt[off] = f16bits(v);
  }
}

// ---------------- spatial permutations ----------------
__device__ __forceinline__ int sigma_fn(int mode, int z, int t, int p) {
  if (t == 0 || mode == 1) return p;
  int i = p >> 5, j = p & 31;
  if (z == 0) {
    if (t == 1) return (j << 5) | (31 - i);
    if (t == 2) return ((31 - i) << 5) | (31 - j);
    return ((31 - j) << 5) | i;
  } else {
    int ib = i & 16, jb = j & 16, il = i & 15, jl = j & 15;
    if (t == 1) return ((ib | jl) << 5) | (jb | (15 - il));
    if (t == 2) return ((ib | (15 - il)) << 5) | (jb | (15 - jl));
    return ((ib | (15 - jl)) << 5) | (jb | il);
  }
}

// ---------------- pipelined multi-term f16 GEMM (r8 config, proven 317us) ----------------
template <int OUTF16>
__global__ __launch_bounds__(512, 2) void gemm_p(
    const u16* __restrict__ Whi,
    const u16* __restrict__ Bx,
    const float* __restrict__ bias, void* __restrict__ dst,
    int nterms, int wselBase, int mode) {
  extern __shared__ u16 lds[];  // 3 x 24576 u16 + 512 f32 bias
  const int tid = threadIdx.x;
  const int lane = tid & 63;
  const int w = tid >> 6;
  const int wr = w >> 2, wc = w & 3;
  const int z = blockIdx.z;
  const int b = blockIdx.x >> 2;
  const int p0 = (blockIdx.x & 3) << 8;
  const int o0 = blockIdx.y << 7;
  const int l15 = lane & 15, l4 = lane >> 4;
  const int s7 = l15 & 7;
  float* blds = (float*)(lds + 73728);

  const int NSTEP = nterms * 12;

  const int baseA0 = (wr * 64 + l15) * 64 + ((l4) ^ s7) * 8;
  const int baseA1 = (wr * 64 + l15) * 64 + ((4 + l4) ^ s7) * 8;
  const int baseB0 = 8192 + (wc * 64 + l15) * 32 + (l4 ^ ((l15 >> 1) & 3)) * 8;
  const int baseB1 = baseB0 + 8192;

  int arow[2], acof[2];
#pragma unroll
  for (int it = 0; it < 2; ++it) {
    int d = it * 512 + tid;
    arow[it] = d >> 3;
    acof[it] = ((d & 7) ^ (arow[it] & 7)) * 8;
  }
  int brow[4], bcof[4];
#pragma unroll
  for (int it = 0; it < 4; ++it) {
    int d = it * 512 + tid;
    int h = d >> 10, rem = d & 1023;
    brow[it] = rem >> 2;
    bcof[it] = h * 32 + (((rem & 3) ^ ((brow[it] >> 1) & 3))) * 8;
  }

  const u16* aptr[2];
  const u16* bptr[4];
  auto setPtrs = [&](int term) {
    int wsel = wselBase + z * 4 + term;
#pragma unroll
    for (int it = 0; it < 2; ++it)
      aptr[it] = Whi + ((size_t)wsel * CDIM + o0 + arow[it]) * CDIM + acof[it];
#pragma unroll
    for (int it = 0; it < 4; ++it) {
      int srow = sigma_fn(mode, z, term, p0 + brow[it]);
      bptr[it] = Bx + ((size_t)b * NP + srow) * CDIM + bcof[it];
    }
  };

  if (tid < nterms * 128) {
    int t = tid >> 7, oo = tid & 127;
    blds[tid] = bias[(size_t)(wselBase + z * 4 + t) * CDIM + o0 + oo];
  }
  asm volatile("s_waitcnt lgkmcnt(0)" ::: "memory");

  f32x4 acc[4][4], racc[4][4];
#pragma unroll
  for (int m = 0; m < 4; ++m)
#pragma unroll
    for (int n = 0; n < 4; ++n) {
      acc[m][n] = (f32x4){0.f, 0.f, 0.f, 0.f};
      racc[m][n] = (f32x4){0.f, 0.f, 0.f, 0.f};
    }

  setPtrs(0);
#pragma unroll
  for (int it = 0; it < 2; ++it) gload_lds16(aptr[it], lds + (it * 512 + tid) * 8);
#pragma unroll
  for (int it = 0; it < 4; ++it) gload_lds16(bptr[it], lds + 8192 + (it * 512 + tid) * 8);
#pragma unroll
  for (int it = 0; it < 2; ++it) aptr[it] += 64;
#pragma unroll
  for (int it = 0; it < 4; ++it) bptr[it] += 64;
#pragma unroll
  for (int it = 0; it < 2; ++it) gload_lds16(aptr[it], lds + 24576 + (it * 512 + tid) * 8);
#pragma unroll
  for (int it = 0; it < 4; ++it) gload_lds16(bptr[it], lds + 24576 + 8192 + (it * 512 + tid) * 8);
#pragma unroll
  for (int it = 0; it < 2; ++it) aptr[it] += 64;
#pragma unroll
  for (int it = 0; it < 4; ++it) bptr[it] += 64;

  int nsk = 2, nst = 0;
  int ckk = 0, cterm = 0;
  int cur = 0, wb = 2;

  for (int s = 0; s < NSTEP; ++s) {
    if (s + 1 < NSTEP) {
      asm volatile("s_waitcnt vmcnt(6)" ::: "memory");
    } else {
      asm volatile("s_waitcnt vmcnt(0)" ::: "memory");
    }
    __builtin_amdgcn_s_barrier();
    asm volatile("" ::: "memory");

    const u16* la = lds + cur * 24576;
    u16* ldst = lds + wb * 24576;
    const bool dostage = (s + 2) < NSTEP;
    if (dostage && nsk == 12) { ++nst; nsk = 0; setPtrs(nst); }

    half8 ah[4], bb[4];
#pragma unroll
    for (int m = 0; m < 4; ++m) ah[m] = *(const half8*)(la + baseA0 + m * 1024);
#pragma unroll
    for (int n = 0; n < 4; ++n) bb[n] = *(const half8*)(la + baseB0 + n * 512);
    if (dostage) {
#pragma unroll
      for (int it = 0; it < 2; ++it) gload_lds16(aptr[it], ldst + (it * 512 + tid) * 8);
    }
    asm volatile("s_waitcnt lgkmcnt(0)" ::: "memory");
    __builtin_amdgcn_s_setprio(1);
#pragma unroll
    for (int m = 0; m < 4; ++m)
#pragma unroll
      for (int n = 0; n < 4; ++n)
        acc[m][n] = __builtin_amdgcn_mfma_f32_16x16x32_f16(ah[m], bb[n], acc[m][n], 0, 0, 0);
    __builtin_amdgcn_s_setprio(0);

#pragma unroll
    for (int m = 0; m < 4; ++m) ah[m] = *(const half8*)(la + baseA1 + m * 1024);
#pragma unroll
    for (int n = 0; n < 4; ++n) bb[n] = *(const half8*)(la + baseB1 + n * 512);
    if (dostage) {
#pragma unroll
      for (int it = 0; it < 4; ++it) gload_lds16(bptr[it], ldst + 8192 + (it * 512 + tid) * 8);
#pragma unroll
      for (int it = 0; it < 2; ++it) aptr[it] += 64;
#pragma unroll
      for (int it = 0; it < 4; ++it) bptr[it] += 64;
      ++nsk;
    }
    asm volatile("s_waitcnt lgkmcnt(0)" ::: "memory");
    __builtin_amdgcn_s_setprio(1);
#pragma unroll
    for (int m = 0; m < 4; ++m)
#pragma unroll
      for (int n = 0; n < 4; ++n)
        acc[m][n] = __builtin_amdgcn_mfma_f32_16x16x32_f16(ah[m], bb[n], acc[m][n], 0, 0, 0);
    __builtin_amdgcn_s_setprio(0);

    if (ckk == 11) {
#pragma unroll
      for (int m = 0; m < 4; ++m) {
        float4 bv = *(const float4*)&blds[cterm * 128 + wr * 64 + m * 16 + l4 * 4];
        float bvf[4] = {bv.x, bv.y, bv.z, bv.w};
#pragma unroll
        for (int n = 0; n < 4; ++n)
#pragma unroll
          for (int r = 0; r < 4; ++r) {
            racc[m][n][r] += fmaxf(0.f, acc[m][n][r] + bvf[r]);
            acc[m][n][r] = 0.f;
          }
      }
    }
    cur = cur == 2 ? 0 : cur + 1;
    wb = wb == 2 ? 0 : wb + 1;
    ++ckk; if (ckk == 12) { ckk = 0; ++cterm; }
  }

#pragma unroll
  for (int m = 0; m < 4; ++m) {
    int rowb = o0 + wr * 64 + m * 16 + l4 * 4;
#pragma unroll
    for (int n = 0; n < 4; ++n) {
      int col = p0 + wc * 64 + n * 16 + l15;
      size_t base = ((size_t)b * CDIM + rowb) * NP + col;
      if (OUTF16) {
        u16* dp = (u16*)dst + (size_t)z * CHW + base;
#pragma unroll
        for (int r = 0; r < 4; ++r) dp[(size_t)r * NP] = f16bits(racc[m][n][r]);
      } else {
        float* dp = (float*)dst + (size_t)z * CHW + base;
#pragma unroll
        for (int r = 0; r < 4; ++r) dp[(size_t)r * NP] = racc[m][n][r];
      }
    }
  }
}

// ---------------- MFMA attention: one wave per (b,c) pair ----------------
// LDS matrices 32x32 f32 stored as [row][chunk of 4 f32], phys chunk = c ^ (row&7) ^ (row>>3)
// (row reads, column reads, and epilogue all <=2-way on banks).
// S^T = mfma(A=K^T, B=Q^T); row-softmax in-register (local 8 + shfl_xor 16/32);
// P -> LDS; out^T = mfma(A=V^T, B=P^T); epilogue unchanged (coalesced aoT write).
__global__ __launch_bounds__(256) void attn_m_k(const u16* __restrict__ hs, u16* __restrict__ aoT) {
  __shared__ float q[4][1024];
  __shared__ float kk[4][1024];
  const int tid = threadIdx.x, w = tid >> 6, lane = tid & 63;
  const int pair0 = blockIdx.x * 4;
  const int b = pair0 / CDIM;
  const int c0 = pair0 % CDIM;
  const int l15 = lane & 15, l4 = lane >> 4;

  // stage: each thread-iter converts one 4-f16 chunk -> one 16B f32 chunk
#pragma unroll
  for (int it = 0; it < 8; ++it) {
    int d4 = it * 256 + tid;
    int pr = d4 >> 9;
    int mat = (d4 >> 8) & 1;
    int off4 = d4 & 255;
    ushort4 hv = *(const ushort4*)&hs[(size_t)mat * CHW + (size_t)(pair0 + pr) * NP + off4 * 4];
    float* dl = mat ? kk[pr] : q[pr];
    int off = off4 * 4;
    int row = off >> 5;
    int ph = ((off & 31) >> 2) ^ (row & 7) ^ (row >> 3);
    float4 v = {f16tof(hv.x), f16tof(hv.y), f16tof(hv.z), f16tof(hv.w)};
    *(float4*)&dl[row * 32 + ph * 4] = v;
  }
  __syncthreads();

  const float* Q = q[w];
  float* KK = kk[w];

  // contiguous 8-k read of row `row` (k = l4*8+e)
  auto rd_row8 = [&](const float* M, int row) -> half8 {
    int rx = (row & 7) ^ (row >> 3);
    float4 a = *(const float4*)&M[row * 32 + ((2 * l4) ^ rx) * 4];
    float4 c = *(const float4*)&M[row * 32 + ((2 * l4 + 1) ^ rx) * 4];
    half8 h;
    h[0] = (_Float16)a.x; h[1] = (_Float16)a.y; h[2] = (_Float16)a.z; h[3] = (_Float16)a.w;
    h[4] = (_Float16)c.x; h[5] = (_Float16)c.y; h[6] = (_Float16)c.z; h[7] = (_Float16)c.w;
    return h;
  };
  // strided 8-row read of column `col` (rows l4*8+e)
  auto rd_col8 = [&](const float* M, int col) -> half8 {
    half8 h;
#pragma unroll
    for (int e = 0; e < 8; ++e) {
      int row = l4 * 8 + e;
      int ph = (col >> 2) ^ (row & 7) ^ (row >> 3);
      h[e] = (_Float16)M[row * 32 + ph * 4 + (col & 3)];
    }
    return h;
  };

  // ---- S^T = K^T @ Q^T : C[mh][it], lane holds S[i=it*16+l15][j=mh*16+l4*4+r]
  half8 bq[2], akk[2];
#pragma unroll
  for (int it = 0; it < 2; ++it) bq[it] = rd_row8(Q, it * 16 + l15);
#pragma unroll
  for (int mh = 0; mh < 2; ++mh) akk[mh] = rd_col8(KK, mh * 16 + l15);
  f32x4 sacc[2][2];
#pragma unroll
  for (int mh = 0; mh < 2; ++mh)
#pragma unroll
    for (int it = 0; it < 2; ++it)
      sacc[mh][it] = __builtin_amdgcn_mfma_f32_16x16x32_f16(
          akk[mh], bq[it], (f32x4){0.f, 0.f, 0.f, 0.f}, 0, 0, 0);

  // ---- row softmax over j (local mh,r + lanes l4 via xor 16/32); P -> KK (K dead)
#pragma unroll
  for (int it = 0; it < 2; ++it) {
    float mx = sacc[0][it][0];
#pragma unroll
    for (int r = 1; r < 4; ++r) mx = fmaxf(mx, sacc[0][it][r]);
#pragma unroll
    for (int r = 0; r < 4; ++r) mx = fmaxf(mx, sacc[1][it][r]);
    mx = fmaxf(mx, __shfl_xor(mx, 16));
    mx = fmaxf(mx, __shfl_xor(mx, 32));
    float pv[2][4];
    float sum = 0.f;
#pragma unroll
    for (int mh = 0; mh < 2; ++mh)
#pragma unroll
      for (int r = 0; r < 4; ++r) {
        pv[mh][r] = expf(sacc[mh][it][r] - mx);
        sum += pv[mh][r];
      }
    sum += __shfl_xor(sum, 16);
    sum += __shfl_xor(sum, 32);
    float inv = 1.f / sum;
    int row = it * 16 + l15;
    int rx = (row & 7) ^ (row >> 3);
#pragma unroll
    for (int mh = 0; mh < 2; ++mh) {
      float4 v = {pv[mh][0] * inv, pv[mh][1] * inv, pv[mh][2] * inv, pv[mh][3] * inv};
      *(float4*)&KK[row * 32 + ((mh * 4 + l4) ^ rx) * 4] = v;
    }
  }

  // ---- out^T = V^T @ P^T : V = Q
  half8 bp[2], av[2];
#pragma unroll
  for (int it = 0; it < 2; ++it) bp[it] = rd_row8(KK, it * 16 + l15);
#pragma unroll
  for (int ht = 0; ht < 2; ++ht) av[ht] = rd_col8(Q, ht * 16 + l15);
  f32x4 oacc[2][2];
#pragma unroll
  for (int ht = 0; ht < 2; ++ht)
#pragma unroll
    for (int it = 0; it < 2; ++it)
      oacc[ht][it] = __builtin_amdgcn_mfma_f32_16x16x32_f16(
          av[ht], bp[it], (f32x4){0.f, 0.f, 0.f, 0.f}, 0, 0, 0);

  // lane holds out[i=it*16+l15][h=ht*16+l4*4+r] -> store to KK as [row=i][col=h]
#pragma unroll
  for (int it = 0; it < 2; ++it) {
    int row = it * 16 + l15;
    int rx = (row & 7) ^ (row >> 3);
#pragma unroll
    for (int ht = 0; ht < 2; ++ht) {
      float4 v = {oacc[ht][it][0], oacc[ht][it][1], oacc[ht][it][2], oacc[ht][it][3]};
      *(float4*)&KK[row * 32 + ((ht * 4 + l4) ^ rx) * 4] = v;
    }
  }
  __syncthreads();

  // epilogue: coalesced aoT[b][p][c0..c0+3]
#pragma unroll
  for (int it = 0; it < 4; ++it) {
    int p = it * 256 + tid;
    int row = p >> 5, col = p & 31;
    int idx = row * 32 + (((col >> 2) ^ (row & 7) ^ (row >> 3)) * 4) + (col & 3);
    ushort4 v;
    v.x = f16bits(kk[0][idx]);
    v.y = f16bits(kk[1][idx]);
    v.z = f16bits(kk[2][idx]);
    v.w = f16bits(kk[3][idx]);
    *(ushort4*)&aoT[((size_t)b * NP + p) * CDIM + c0] = v;
  }
}

extern "C" void kernel_launch(void* const* d_in, const int* in_sizes, int n_in,
                              void* d_out, int out_size, void* d_ws, size_t ws_size,
                              hipStream_t stream) {
  (void)in_sizes; (void)n_in; (void)out_size; (void)ws_size;
  const float* x = (const float*)d_in[0];
  const float* Ws = (const float*)d_in[1];
  const float* bs = (const float*)d_in[2];
  float* out = (float*)d_out;
  char* ws = (char*)d_ws;

  u16* XT  = (u16*)(ws + XT_OFF);
  u16* hs  = (u16*)(ws + HS_OFF);    // f16 hs11 (z0), hs111 (z1)
  u16* Whi = (u16*)(ws + WHI_OFF);
  u16* aoT = (u16*)(ws + XT_OFF);    // aliases XT (dead after stage-1)

  cast_w_k<<<5184, 256, 0, stream>>>(Ws, Whi);
  transpose_f16_k<<<dim3(32, 24, 32), 256, 0, stream>>>(x, XT);
  // stage-1: hs11 (z=0, W0..3) and hs111 (z=1, W4..7); 128x256 tiles, f16 output
  gemm_p<1><<<dim3(128, 6, 2), 512, 149504, stream>>>(Whi, XT, bs, (void*)hs, 4, 0, 0);
  attn_m_k<<<6144, 256, 0, stream>>>(hs, aoT);
  // final conv: relu(W8 @ attout + b8) -> d_out (fp32)
  gemm_p<0><<<dim3(128, 6, 1), 512, 149504, stream>>>(Whi, aoT, bs, (void*)out, 1, 8, 1);
}

// Round 12
// 503.944 us; speedup vs baseline: 1.7518x; 1.0090x over previous
//
#include <hip/hip_runtime.h>
#include <hip/hip_fp16.h>

typedef unsigned short u16;
typedef unsigned int u32;
typedef float f32x4 __attribute__((ext_vector_type(4)));
typedef _Float16 half8 __attribute__((ext_vector_type(8)));
typedef unsigned short u16x4 __attribute__((ext_vector_type(4)));

#define CDIM 768
#define NP 1024
#define NB 32

static constexpr size_t CHW = (size_t)NB * CDIM * NP;  // 25,165,824

// workspace layout (bytes)
static constexpr size_t XT_OFF  = 0;                         // f16 [b][p][c]; later reused as aoT f16
static constexpr size_t HS_OFF  = CHW * 2;                   // f16 hs11, hs111
static constexpr size_t WHI_OFF = HS_OFF + CHW * 4;          // f16 weights

__device__ __forceinline__ u16 f16bits(float f) {
  return __half_as_ushort(__float2half_rn(f));
}
__device__ __forceinline__ float f16tof(u16 b) {
  __half_raw hr; hr.x = b; return __half2float(__half(hr));
}
__device__ __forceinline__ u32 pk2(u32 p, float a, float b) {
  float x = f16tof((u16)(p & 0xffff)) + a;
  float y = f16tof((u16)(p >> 16)) + b;
  return (u32)f16bits(x) | ((u32)f16bits(y) << 16);
}

typedef __attribute__((address_space(1))) void gv_t;
typedef __attribute__((address_space(3))) void lv_t;
__device__ __forceinline__ void gload_lds16(const void* g, void* l) {
  __builtin_amdgcn_global_load_lds((gv_t*)g, (lv_t*)l, 16, 0, 0);
}

// ---------------- cast W (fp32 -> f16) ----------------
__global__ __launch_bounds__(256) void cast_w_k(const float* __restrict__ W,
                                                u16* __restrict__ hi) {
  int i = blockIdx.x * 256 + threadIdx.x;
  float4 v = ((const float4*)W)[i];
  u16x4 h4 = {f16bits(v.x), f16bits(v.y), f16bits(v.z), f16bits(v.w)};
  ((u16x4*)hi)[i] = h4;
}

// ---------------- transpose + f16 cast: src fp32 [b][c][p] -> dst f16 [b][p][c] ----------------
__global__ __launch_bounds__(256) void transpose_f16_k(const float* __restrict__ src,
                                                       u16* __restrict__ dxt) {
  __shared__ float tle[32][33];
  const int b = blockIdx.z, c0 = blockIdx.y * 32, p0 = blockIdx.x * 32;
  const int tid = threadIdx.x;
  const int lr = tid >> 5, lc = tid & 31;
  const float* s = src + ((size_t)b * CDIM + c0) * NP + p0;
#pragma unroll
  for (int it = 0; it < 4; ++it) {
    int c = it * 8 + lr;
    tle[c][lc] = s[(size_t)c * NP + lc];
  }
  __syncthreads();
#pragma unroll
  for (int it = 0; it < 4; ++it) {
    int p = it * 8 + lr;
    float v = tle[lc][p];
    size_t off = ((size_t)b * NP + p0 + p) * CDIM + c0 + lc;
    dxt[off] = f16bits(v);
  }
}

// ---------------- spatial permutations ----------------
__device__ __forceinline__ int sigma_fn(int mode, int z, int t, int p) {
  if (t == 0 || mode == 1) return p;
  int i = p >> 5, j = p & 31;
  if (z == 0) {
    if (t == 1) return (j << 5) | (31 - i);
    if (t == 2) return ((31 - i) << 5) | (31 - j);
    return ((31 - j) << 5) | i;
  } else {
    int ib = i & 16, jb = j & 16, il = i & 15, jl = j & 15;
    if (t == 1) return ((ib | jl) << 5) | (jb | (15 - il));
    if (t == 2) return ((ib | (15 - il)) << 5) | (jb | (15 - jl));
    return ((ib | (15 - jl)) << 5) | (jb | il);
  }
}

// ---------------- 256x256-tile multi-term f16 GEMM, r8 schedule ----------------
// 512 threads = 8 waves (2M x 4N), wave tile 128x64, BK=32.
// 3 LDS buffers x 32KB: A [0,8192) u16 = [256 rows][4 chunks of 8], 64B stride,
// phys = logical ^ ((row>>1)&3) (proven 0-conflict); B [8192,16384) identical. + bias.
// Depth-2 prefetch, counted vmcnt(4)/step (4 loads/thread/step), 1 barrier/step.
// acc f32 (AGPR); multi-term racc packed f16x2 (numerics proven in r9).
template <int OUTF16, int NTERMS>
__global__ __launch_bounds__(512, 2) void gemm_r(
    const u16* __restrict__ Whi,
    const u16* __restrict__ Bx,
    const float* __restrict__ bias, void* __restrict__ dst,
    int wselBase, int mode) {
  extern __shared__ u16 lds[];  // 3 x 16384 u16 + NTERMS*256 f32 bias
  const int tid = threadIdx.x;
  const int lane = tid & 63;
  const int w = tid >> 6;
  const int wr = w >> 2, wc = w & 3;
  const int z = blockIdx.z;
  const int b = blockIdx.x >> 2;
  const int p0 = (blockIdx.x & 3) << 8;
  const int o0 = blockIdx.y << 8;
  const int l15 = lane & 15, l4 = lane >> 4;
  float* blds = (float*)(lds + 49152);
  const int NSTEP = NTERMS * 24;

  // LDS read bases (u16 units); A frag m: +m*512 (16 rows), B frag n: +n*512.
  // XOR key (row>>1)&3 invariant under +16 rows.
  const int rA = wr * 128 + l15;
  const int baseA = rA * 32 + (l4 ^ ((rA >> 1) & 3)) * 8;
  const int rB = wc * 64 + l15;
  const int baseB = 8192 + rB * 32 + (l4 ^ ((rB >> 1) & 3)) * 8;

  // staging decode: slot d = it*512+tid -> row = d>>2 (0..255), phys chunk = d&3,
  // logical = phys ^ ((row>>1)&3); dest = linear d*16B (gload_lds lane rule)
  int srow[2], scof[2];
#pragma unroll
  for (int it = 0; it < 2; ++it) {
    int d = it * 512 + tid;
    srow[it] = d >> 2;
    scof[it] = ((d & 3) ^ ((srow[it] >> 1) & 3)) * 8;
  }
  const u16* aptr[2];
  const u16* bptr[2];
  auto setPtrs = [&](int term) {
    int wsel = wselBase + z * 4 + term;
#pragma unroll
    for (int it = 0; it < 2; ++it) {
      aptr[it] = Whi + ((size_t)wsel * CDIM + o0 + srow[it]) * CDIM + scof[it];
      int srw = sigma_fn(mode, z, term, p0 + srow[it]);
      bptr[it] = Bx + ((size_t)b * NP + srw) * CDIM + scof[it];
    }
  };
  auto stageA = [&](u16* ldst) {
    gload_lds16(aptr[0], ldst + tid * 8);
    gload_lds16(aptr[1], ldst + 4096 + tid * 8);
    aptr[0] += 32; aptr[1] += 32;
  };
  auto stageB = [&](u16* ldst) {
    gload_lds16(bptr[0], ldst + 8192 + tid * 8);
    gload_lds16(bptr[1], ldst + 12288 + tid * 8);
    bptr[0] += 32; bptr[1] += 32;
  };

  // bias -> LDS
  for (int i = tid; i < NTERMS * 256; i += 512)
    blds[i] = bias[(size_t)(wselBase + z * 4 + (i >> 8)) * CDIM + o0 + (i & 255)];
  asm volatile("s_waitcnt lgkmcnt(0)" ::: "memory");

  f32x4 acc[8][4];
#pragma unroll
  for (int mi = 0; mi < 8; ++mi)
#pragma unroll
    for (int ni = 0; ni < 4; ++ni) acc[mi][ni] = (f32x4){0.f, 0.f, 0.f, 0.f};
  u32 rp[8][4][2];
  if (NTERMS > 1) {
#pragma unroll
    for (int mi = 0; mi < 8; ++mi)
#pragma unroll
      for (int ni = 0; ni < 4; ++ni) { rp[mi][ni][0] = 0u; rp[mi][ni][1] = 0u; }
  }

  // prologue: stage steps 0,1 into bufs 0,1
  setPtrs(0);
  stageA(lds); stageB(lds);
  stageA(lds + 16384); stageB(lds + 16384);

  int nsk = 2, nst = 0;   // staged steps in current term / its term
  int ckk = 0, cterm = 0; // consumed k-step / term
  int cur = 0, wb = 2;

  for (int s = 0; s < NSTEP; ++s) {
    if (s + 1 < NSTEP) {
      asm volatile("s_waitcnt vmcnt(4)" ::: "memory");
    } else {
      asm volatile("s_waitcnt vmcnt(0)" ::: "memory");
    }
    __builtin_amdgcn_s_barrier();
    asm volatile("" ::: "memory");

    const u16* la = lds + cur * 16384;
    u16* ldst = lds + wb * 16384;
    const bool dostage = (s + 2) < NSTEP;
    if (dostage && nsk == 24) { ++nst; nsk = 0; setPtrs(nst); }

    half8 af[4], bf[4];
    // ======== phase 0: B all + A m0-3; stage A(s+2); 16 MFMA ========
#pragma unroll
    for (int n = 0; n < 4; ++n) bf[n] = *(const half8*)(la + baseB + n * 512);
#pragma unroll
    for (int m = 0; m < 4; ++m) af[m] = *(const half8*)(la + baseA + m * 512);
    if (dostage) stageA(ldst);
    asm volatile("s_waitcnt lgkmcnt(0)" ::: "memory");
    __builtin_amdgcn_s_setprio(1);
#pragma unroll
    for (int m = 0; m < 4; ++m)
#pragma unroll
      for (int n = 0; n < 4; ++n)
        acc[m][n] = __builtin_amdgcn_mfma_f32_16x16x32_f16(af[m], bf[n], acc[m][n], 0, 0, 0);
    __builtin_amdgcn_s_setprio(0);

    // ======== phase 1: A m4-7; stage B(s+2); 16 MFMA ========
#pragma unroll
    for (int m = 0; m < 4; ++m) af[m] = *(const half8*)(la + baseA + (4 + m) * 512);
    if (dostage) { stageB(ldst); ++nsk; }
    asm volatile("s_waitcnt lgkmcnt(0)" ::: "memory");
    __builtin_amdgcn_s_setprio(1);
#pragma unroll
    for (int m = 0; m < 4; ++m)
#pragma unroll
      for (int n = 0; n < 4; ++n)
        acc[4 + m][n] = __builtin_amdgcn_mfma_f32_16x16x32_f16(af[m], bf[n], acc[4 + m][n], 0, 0, 0);
    __builtin_amdgcn_s_setprio(0);

    if (NTERMS > 1 && ckk == 23) {  // term boundary: relu(acc+bias) -> packed racc
#pragma unroll
      for (int mi = 0; mi < 8; ++mi) {
        float4 bv = *(const float4*)&blds[cterm * 256 + wr * 128 + mi * 16 + l4 * 4];
#pragma unroll
        for (int ni = 0; ni < 4; ++ni) {
          rp[mi][ni][0] = pk2(rp[mi][ni][0], fmaxf(0.f, acc[mi][ni][0] + bv.x),
                                             fmaxf(0.f, acc[mi][ni][1] + bv.y));
          rp[mi][ni][1] = pk2(rp[mi][ni][1], fmaxf(0.f, acc[mi][ni][2] + bv.z),
                                             fmaxf(0.f, acc[mi][ni][3] + bv.w));
          acc[mi][ni] = (f32x4){0.f, 0.f, 0.f, 0.f};
        }
      }
    }
    cur = cur == 2 ? 0 : cur + 1;
    wb = wb == 2 ? 0 : wb + 1;
    ++ckk; if (ckk == 24) { ckk = 0; ++cterm; }
  }

  // epilogue: row = o0+wr*128+mi*16+l4*4+r, col = p0+wc*64+ni*16+l15
#pragma unroll
  for (int mi = 0; mi < 8; ++mi) {
    int rowb = o0 + wr * 128 + mi * 16 + l4 * 4;
#pragma unroll
    for (int ni = 0; ni < 4; ++ni) {
      int col = p0 + wc * 64 + ni * 16 + l15;
      size_t base = ((size_t)b * CDIM + rowb) * NP + col;
      if (NTERMS > 1) {
        u16* dp = (u16*)dst + (size_t)z * CHW + base;
        dp[0 * NP] = (u16)(rp[mi][ni][0] & 0xffff);
        dp[1 * NP] = (u16)(rp[mi][ni][0] >> 16);
        dp[2 * NP] = (u16)(rp[mi][ni][1] & 0xffff);
        dp[3 * NP] = (u16)(rp[mi][ni][1] >> 16);
      } else {
        float4 bv = *(const float4*)&blds[wr * 128 + mi * 16 + l4 * 4];
        float bvf[4] = {bv.x, bv.y, bv.z, bv.w};
        float* dp = (float*)dst + (size_t)z * CHW + base;
#pragma unroll
        for (int r = 0; r < 4; ++r)
          dp[(size_t)r * NP] = fmaxf(0.f, acc[mi][ni][r] + bvf[r]);
      }
    }
  }
}

// ---------------- MFMA attention: one wave per (b,c) pair (r11, proven) ----------------
__global__ __launch_bounds__(256) void attn_m_k(const u16* __restrict__ hs, u16* __restrict__ aoT) {
  __shared__ float q[4][1024];
  __shared__ float kk[4][1024];
  const int tid = threadIdx.x, w = tid >> 6, lane = tid & 63;
  const int pair0 = blockIdx.x * 4;
  const int b = pair0 / CDIM;
  const int c0 = pair0 % CDIM;
  const int l15 = lane & 15, l4 = lane >> 4;

#pragma unroll
  for (int it = 0; it < 8; ++it) {
    int d4 = it * 256 + tid;
    int pr = d4 >> 9;
    int mat = (d4 >> 8) & 1;
    int off4 = d4 & 255;
    ushort4 hv = *(const ushort4*)&hs[(size_t)mat * CHW + (size_t)(pair0 + pr) * NP + off4 * 4];
    float* dl = mat ? kk[pr] : q[pr];
    int off = off4 * 4;
    int row = off >> 5;
    int ph = ((off & 31) >> 2) ^ (row & 7) ^ (row >> 3);
    float4 v = {f16tof(hv.x), f16tof(hv.y), f16tof(hv.z), f16tof(hv.w)};
    *(float4*)&dl[row * 32 + ph * 4] = v;
  }
  __syncthreads();

  const float* Q = q[w];
  float* KK = kk[w];

  auto rd_row8 = [&](const float* M, int row) -> half8 {
    int rx = (row & 7) ^ (row >> 3);
    float4 a = *(const float4*)&M[row * 32 + ((2 * l4) ^ rx) * 4];
    float4 c = *(const float4*)&M[row * 32 + ((2 * l4 + 1) ^ rx) * 4];
    half8 h;
    h[0] = (_Float16)a.x; h[1] = (_Float16)a.y; h[2] = (_Float16)a.z; h[3] = (_Float16)a.w;
    h[4] = (_Float16)c.x; h[5] = (_Float16)c.y; h[6] = (_Float16)c.z; h[7] = (_Float16)c.w;
    return h;
  };
  auto rd_col8 = [&](const float* M, int col) -> half8 {
    half8 h;
#pragma unroll
    for (int e = 0; e < 8; ++e) {
      int row = l4 * 8 + e;
      int ph = (col >> 2) ^ (row & 7) ^ (row >> 3);
      h[e] = (_Float16)M[row * 32 + ph * 4 + (col & 3)];
    }
    return h;
  };

  half8 bq[2], akk[2];
#pragma unroll
  for (int it = 0; it < 2; ++it) bq[it] = rd_row8(Q, it * 16 + l15);
#pragma unroll
  for (int mh = 0; mh < 2; ++mh) akk[mh] = rd_col8(KK, mh * 16 + l15);
  f32x4 sacc[2][2];
#pragma unroll
  for (int mh = 0; mh < 2; ++mh)
#pragma unroll
    for (int it = 0; it < 2; ++it)
      sacc[mh][it] = __builtin_amdgcn_mfma_f32_16x16x32_f16(
          akk[mh], bq[it], (f32x4){0.f, 0.f, 0.f, 0.f}, 0, 0, 0);

#pragma unroll
  for (int it = 0; it < 2; ++it) {
    float mx = sacc[0][it][0];
#pragma unroll
    for (int r = 1; r < 4; ++r) mx = fmaxf(mx, sacc[0][it][r]);
#pragma unroll
    for (int r = 0; r < 4; ++r) mx = fmaxf(mx, sacc[1][it][r]);
    mx = fmaxf(mx, __shfl_xor(mx, 16));
    mx = fmaxf(mx, __shfl_xor(mx, 32));
    float pv[2][4];
    float sum = 0.f;
#pragma unroll
    for (int mh = 0; mh < 2; ++mh)
#pragma unroll
      for (int r = 0; r < 4; ++r) {
        pv[mh][r] = expf(sacc[mh][it][r] - mx);
        sum += pv[mh][r];
      }
    sum += __shfl_xor(sum, 16);
    sum += __shfl_xor(sum, 32);
    float inv = 1.f / sum;
    int row = it * 16 + l15;
    int rx = (row & 7) ^ (row >> 3);
#pragma unroll
    for (int mh = 0; mh < 2; ++mh) {
      float4 v = {pv[mh][0] * inv, pv[mh][1] * inv, pv[mh][2] * inv, pv[mh][3] * inv};
      *(float4*)&KK[row * 32 + ((mh * 4 + l4) ^ rx) * 4] = v;
    }
  }

  half8 bp[2], av[2];
#pragma unroll
  for (int it = 0; it < 2; ++it) bp[it] = rd_row8(KK, it * 16 + l15);
#pragma unroll
  for (int ht = 0; ht < 2; ++ht) av[ht] = rd_col8(Q, ht * 16 + l15);
  f32x4 oacc[2][2];
#pragma unroll
  for (int ht = 0; ht < 2; ++ht)
#pragma unroll
    for (int it = 0; it < 2; ++it)
      oacc[ht][it] = __builtin_amdgcn_mfma_f32_16x16x32_f16(
          av[ht], bp[it], (f32x4){0.f, 0.f, 0.f, 0.f}, 0, 0, 0);

#pragma unroll
  for (int it = 0; it < 2; ++it) {
    int row = it * 16 + l15;
    int rx = (row & 7) ^ (row >> 3);
#pragma unroll
    for (int ht = 0; ht < 2; ++ht) {
      float4 v = {oacc[ht][it][0], oacc[ht][it][1], oacc[ht][it][2], oacc[ht][it][3]};
      *(float4*)&KK[row * 32 + ((ht * 4 + l4) ^ rx) * 4] = v;
    }
  }
  __syncthreads();

#pragma unroll
  for (int it = 0; it < 4; ++it) {
    int p = it * 256 + tid;
    int row = p >> 5, col = p & 31;
    int idx = row * 32 + (((col >> 2) ^ (row & 7) ^ (row >> 3)) * 4) + (col & 3);
    ushort4 v;
    v.x = f16bits(kk[0][idx]);
    v.y = f16bits(kk[1][idx]);
    v.z = f16bits(kk[2][idx]);
    v.w = f16bits(kk[3][idx]);
    *(ushort4*)&aoT[((size_t)b * NP + p) * CDIM + c0] = v;
  }
}

extern "C" void kernel_launch(void* const* d_in, const int* in_sizes, int n_in,
                              void* d_out, int out_size, void* d_ws, size_t ws_size,
                              hipStream_t stream) {
  (void)in_sizes; (void)n_in; (void)out_size; (void)ws_size;
  const float* x = (const float*)d_in[0];
  const float* Ws = (const float*)d_in[1];
  const float* bs = (const float*)d_in[2];
  float* out = (float*)d_out;
  char* ws = (char*)d_ws;

  u16* XT  = (u16*)(ws + XT_OFF);
  u16* hs  = (u16*)(ws + HS_OFF);    // f16 hs11 (z0), hs111 (z1)
  u16* Whi = (u16*)(ws + WHI_OFF);
  u16* aoT = (u16*)(ws + XT_OFF);    // aliases XT (dead after stage-1)

  cast_w_k<<<5184, 256, 0, stream>>>(Ws, Whi);
  transpose_f16_k<<<dim3(32, 24, 32), 256, 0, stream>>>(x, XT);
  // stage-1: hs11 (z=0, W0..3) and hs111 (z=1, W4..7); 256x256 tiles, f16 out
  gemm_r<1, 4><<<dim3(128, 3, 2), 512, 102400, stream>>>(Whi, XT, bs, (void*)hs, 0, 0);
  attn_m_k<<<6144, 256, 0, stream>>>(hs, aoT);
  // final conv: relu(W8 @ attout + b8) -> d_out (fp32)
  gemm_r<0, 1><<<dim3(128, 3, 1), 512, 99328, stream>>>(Whi, aoT, bs, (void*)out, 8, 1);
}

// Round 13
// 464.766 us; speedup vs baseline: 1.8994x; 1.0843x over previous
//
#include <hip/hip_runtime.h>
#include <hip/hip_fp16.h>

typedef unsigned short u16;
typedef unsigned int u32;
typedef float f32x4 __attribute__((ext_vector_type(4)));
typedef _Float16 half8 __attribute__((ext_vector_type(8)));
typedef unsigned short u16x4 __attribute__((ext_vector_type(4)));

#define CDIM 768
#define NP 1024
#define NB 32

static constexpr size_t PBATCH = (size_t)CDIM * NP;   // per-batch image elems
static constexpr size_t CHW = (size_t)NB * PBATCH;    // 25,165,824

// workspace layout (bytes)
static constexpr size_t XT_OFF  = 0;                  // f16 tiled [b][c>>4][p][c&15]; reused as aoT
static constexpr size_t HS_OFF  = CHW * 2;            // f16 hs11, hs111 ([z][b][c][p])
static constexpr size_t WHI_OFF = HS_OFF + CHW * 4;   // f16 weights

__device__ __forceinline__ u16 f16bits(float f) {
  return __half_as_ushort(__float2half_rn(f));
}
__device__ __forceinline__ float f16tof(u16 b) {
  __half_raw hr; hr.x = b; return __half2float(__half(hr));
}
__device__ __forceinline__ int akey(int r) { return ((r >> 1) & 3) ^ ((r >> 3) & 3); }

typedef __attribute__((address_space(1))) void gv_t;
typedef __attribute__((address_space(3))) void lv_t;
__device__ __forceinline__ void gload_lds16(const void* g, void* l) {
  __builtin_amdgcn_global_load_lds((gv_t*)g, (lv_t*)l, 16, 0, 0);
}

// ---------------- cast W (fp32 -> f16) ----------------
__global__ __launch_bounds__(256) void cast_w_k(const float* __restrict__ W,
                                                u16* __restrict__ hi) {
  int i = blockIdx.x * 256 + threadIdx.x;
  float4 v = ((const float4*)W)[i];
  u16x4 h4 = {f16bits(v.x), f16bits(v.y), f16bits(v.z), f16bits(v.w)};
  ((u16x4*)hi)[i] = h4;
}

// ---------------- transpose + f16 cast: fp32 [b][c][p] -> f16 tiled [b][c>>4][p][c&15] ----------------
__global__ __launch_bounds__(256) void transpose_f16_k(const float* __restrict__ src,
                                                       u16* __restrict__ dxt) {
  __shared__ float tle[32][33];
  const int b = blockIdx.z, c0 = blockIdx.y * 32, p0 = blockIdx.x * 32;
  const int tid = threadIdx.x;
  const int lr = tid >> 5, lc = tid & 31;
  const float* s = src + ((size_t)b * CDIM + c0) * NP + p0;
#pragma unroll
  for (int it = 0; it < 4; ++it) {
    int c = it * 8 + lr;
    tle[c][lc] = s[(size_t)c * NP + lc];
  }
  __syncthreads();
#pragma unroll
  for (int it = 0; it < 4; ++it) {
    int p = p0 + it * 8 + lr;
    float v = tle[lc][it * 8 + lr];
    int c = c0 + lc;
    size_t off = (size_t)b * PBATCH + (size_t)(c >> 4) * (NP * 16) + (size_t)p * 16 + (c & 15);
    dxt[off] = f16bits(v);
  }
}

// ---------------- spatial permutations ----------------
__device__ __forceinline__ int sigma_fn(int mode, int z, int t, int p) {
  if (t == 0 || mode == 1) return p;
  int i = p >> 5, j = p & 31;
  if (z == 0) {
    if (t == 1) return (j << 5) | (31 - i);
    if (t == 2) return ((31 - i) << 5) | (31 - j);
    return ((31 - j) << 5) | i;
  } else {
    int ib = i & 16, jb = j & 16, il = i & 15, jl = j & 15;
    if (t == 1) return ((ib | jl) << 5) | (jb | (15 - il));
    if (t == 2) return ((ib | (15 - il)) << 5) | (jb | (15 - jl));
    return ((ib | (15 - jl)) << 5) | (jb | il);
  }
}

// ---------------- pipelined multi-term f16 GEMM (r8 config, 317us proven; B tiled) ----------------
template <int OUTF16>
__global__ __launch_bounds__(512, 2) void gemm_p(
    const u16* __restrict__ Whi,
    const u16* __restrict__ Bx,
    const float* __restrict__ bias, void* __restrict__ dst,
    int nterms, int wselBase, int mode) {
  extern __shared__ u16 lds[];  // 3 x 24576 u16 + 512 f32 bias
  const int tid = threadIdx.x;
  const int lane = tid & 63;
  const int w = tid >> 6;
  const int wr = w >> 2, wc = w & 3;
  const int z = blockIdx.z;
  const int b = blockIdx.x >> 2;
  const int p0 = (blockIdx.x & 3) << 8;
  const int o0 = blockIdx.y << 7;
  const int l15 = lane & 15, l4 = lane >> 4;
  const int s7 = l15 & 7;
  float* blds = (float*)(lds + 73728);

  const int NSTEP = nterms * 12;

  const int baseA0 = (wr * 64 + l15) * 64 + ((l4) ^ s7) * 8;
  const int baseA1 = (wr * 64 + l15) * 64 + ((4 + l4) ^ s7) * 8;
  const int baseB0 = 8192 + (wc * 64 + l15) * 32 + (l4 ^ ((l15 >> 1) & 3)) * 8;
  const int baseB1 = baseB0 + 8192;

  int arow[2], acof[2];
#pragma unroll
  for (int it = 0; it < 2; ++it) {
    int d = it * 512 + tid;
    arow[it] = d >> 3;
    acof[it] = ((d & 7) ^ (arow[it] & 7)) * 8;
  }
  int brow[4], bcof[4];
#pragma unroll
  for (int it = 0; it < 4; ++it) {
    int d = it * 512 + tid;
    int h = d >> 10, rem = d & 1023;
    brow[it] = rem >> 2;
    bcof[it] = h * 32 + (((rem & 3) ^ ((brow[it] >> 1) & 3))) * 8;
  }

  const u16* aptr[2];
  const u16* bptr[4];
  auto setPtrs = [&](int term) {
    int wsel = wselBase + z * 4 + term;
#pragma unroll
    for (int it = 0; it < 2; ++it)
      aptr[it] = Whi + ((size_t)wsel * CDIM + o0 + arow[it]) * CDIM + acof[it];
#pragma unroll
    for (int it = 0; it < 4; ++it) {
      int srow = sigma_fn(mode, z, term, p0 + brow[it]);
      int cc = bcof[it];
      bptr[it] = Bx + (size_t)b * PBATCH + (size_t)(cc >> 4) * (NP * 16) + (size_t)srow * 16 + (cc & 15);
    }
  };

  if (tid < nterms * 128) {
    int t = tid >> 7, oo = tid & 127;
    blds[tid] = bias[(size_t)(wselBase + z * 4 + t) * CDIM + o0 + oo];
  }
  asm volatile("s_waitcnt lgkmcnt(0)" ::: "memory");

  f32x4 acc[4][4], racc[4][4];
#pragma unroll
  for (int m = 0; m < 4; ++m)
#pragma unroll
    for (int n = 0; n < 4; ++n) {
      acc[m][n] = (f32x4){0.f, 0.f, 0.f, 0.f};
      racc[m][n] = (f32x4){0.f, 0.f, 0.f, 0.f};
    }

  setPtrs(0);
#pragma unroll
  for (int it = 0; it < 2; ++it) gload_lds16(aptr[it], lds + (it * 512 + tid) * 8);
#pragma unroll
  for (int it = 0; it < 4; ++it) gload_lds16(bptr[it], lds + 8192 + (it * 512 + tid) * 8);
#pragma unroll
  for (int it = 0; it < 2; ++it) aptr[it] += 64;
#pragma unroll
  for (int it = 0; it < 4; ++it) bptr[it] += 65536;
#pragma unroll
  for (int it = 0; it < 2; ++it) gload_lds16(aptr[it], lds + 24576 + (it * 512 + tid) * 8);
#pragma unroll
  for (int it = 0; it < 4; ++it) gload_lds16(bptr[it], lds + 24576 + 8192 + (it * 512 + tid) * 8);
#pragma unroll
  for (int it = 0; it < 2; ++it) aptr[it] += 64;
#pragma unroll
  for (int it = 0; it < 4; ++it) bptr[it] += 65536;

  int nsk = 2, nst = 0;
  int ckk = 0, cterm = 0;
  int cur = 0, wb = 2;

  for (int s = 0; s < NSTEP; ++s) {
    if (s + 1 < NSTEP) {
      asm volatile("s_waitcnt vmcnt(6)" ::: "memory");
    } else {
      asm volatile("s_waitcnt vmcnt(0)" ::: "memory");
    }
    __builtin_amdgcn_s_barrier();
    asm volatile("" ::: "memory");

    const u16* la = lds + cur * 24576;
    u16* ldst = lds + wb * 24576;
    const bool dostage = (s + 2) < NSTEP;
    if (dostage && nsk == 12) { ++nst; nsk = 0; setPtrs(nst); }

    half8 ah[4], bb[4];
#pragma unroll
    for (int m = 0; m < 4; ++m) ah[m] = *(const half8*)(la + baseA0 + m * 1024);
#pragma unroll
    for (int n = 0; n < 4; ++n) bb[n] = *(const half8*)(la + baseB0 + n * 512);
    if (dostage) {
#pragma unroll
      for (int it = 0; it < 2; ++it) gload_lds16(aptr[it], ldst + (it * 512 + tid) * 8);
    }
    asm volatile("s_waitcnt lgkmcnt(0)" ::: "memory");
    __builtin_amdgcn_s_setprio(1);
#pragma unroll
    for (int m = 0; m < 4; ++m)
#pragma unroll
      for (int n = 0; n < 4; ++n)
        acc[m][n] = __builtin_amdgcn_mfma_f32_16x16x32_f16(ah[m], bb[n], acc[m][n], 0, 0, 0);
    __builtin_amdgcn_s_setprio(0);

#pragma unroll
    for (int m = 0; m < 4; ++m) ah[m] = *(const half8*)(la + baseA1 + m * 1024);
#pragma unroll
    for (int n = 0; n < 4; ++n) bb[n] = *(const half8*)(la + baseB1 + n * 512);
    if (dostage) {
#pragma unroll
      for (int it = 0; it < 4; ++it) gload_lds16(bptr[it], ldst + 8192 + (it * 512 + tid) * 8);
#pragma unroll
      for (int it = 0; it < 2; ++it) aptr[it] += 64;
#pragma unroll
      for (int it = 0; it < 4; ++it) bptr[it] += 65536;
      ++nsk;
    }
    asm volatile("s_waitcnt lgkmcnt(0)" ::: "memory");
    __builtin_amdgcn_s_setprio(1);
#pragma unroll
    for (int m = 0; m < 4; ++m)
#pragma unroll
      for (int n = 0; n < 4; ++n)
        acc[m][n] = __builtin_amdgcn_mfma_f32_16x16x32_f16(ah[m], bb[n], acc[m][n], 0, 0, 0);
    __builtin_amdgcn_s_setprio(0);

    if (ckk == 11) {
#pragma unroll
      for (int m = 0; m < 4; ++m) {
        float4 bv = *(const float4*)&blds[cterm * 128 + wr * 64 + m * 16 + l4 * 4];
        float bvf[4] = {bv.x, bv.y, bv.z, bv.w};
#pragma unroll
        for (int n = 0; n < 4; ++n)
#pragma unroll
          for (int r = 0; r < 4; ++r) {
            racc[m][n][r] += fmaxf(0.f, acc[m][n][r] + bvf[r]);
            acc[m][n][r] = 0.f;
          }
      }
    }
    cur = cur == 2 ? 0 : cur + 1;
    wb = wb == 2 ? 0 : wb + 1;
    ++ckk; if (ckk == 12) { ckk = 0; ++cterm; }
  }

#pragma unroll
  for (int m = 0; m < 4; ++m) {
    int rowb = o0 + wr * 64 + m * 16 + l4 * 4;
#pragma unroll
    for (int n = 0; n < 4; ++n) {
      int col = p0 + wc * 64 + n * 16 + l15;
      size_t base = ((size_t)b * CDIM + rowb) * NP + col;
      if (OUTF16) {
        u16* dp = (u16*)dst + (size_t)z * CHW + base;
#pragma unroll
        for (int r = 0; r < 4; ++r) dp[(size_t)r * NP] = f16bits(racc[m][n][r]);
      } else {
        float* dp = (float*)dst + (size_t)z * CHW + base;
#pragma unroll
        for (int r = 0; r < 4; ++r) dp[(size_t)r * NP] = racc[m][n][r];
      }
    }
  }
}

// ---------------- 256x256-tile f16 GEMM (r12 config; used for final conv; B tiled) ----------------
__global__ __launch_bounds__(512, 2) void gemm_r(
    const u16* __restrict__ Whi,
    const u16* __restrict__ Bx,
    const float* __restrict__ bias, float* __restrict__ dst,
    int wselBase) {
  extern __shared__ u16 lds[];  // 3 x 16384 u16 + 256 f32 bias
  const int tid = threadIdx.x;
  const int lane = tid & 63;
  const int w = tid >> 6;
  const int wr = w >> 2, wc = w & 3;
  const int b = blockIdx.x >> 2;
  const int p0 = (blockIdx.x & 3) << 8;
  const int o0 = blockIdx.y << 8;
  const int l15 = lane & 15, l4 = lane >> 4;
  float* blds = (float*)(lds + 49152);
  const int NSTEP = 24;

  const int rA = wr * 128 + l15;
  const int baseA = rA * 32 + (l4 ^ ((rA >> 1) & 3)) * 8;
  const int rB = wc * 64 + l15;
  const int baseB = 8192 + rB * 32 + (l4 ^ ((rB >> 1) & 3)) * 8;

  int srow[2], scof[2];
#pragma unroll
  for (int it = 0; it < 2; ++it) {
    int d = it * 512 + tid;
    srow[it] = d >> 2;
    scof[it] = ((d & 3) ^ ((srow[it] >> 1) & 3)) * 8;
  }
  const u16* aptr[2];
  const u16* bptr[2];
  {
    int wsel = wselBase;
#pragma unroll
    for (int it = 0; it < 2; ++it) {
      aptr[it] = Whi + ((size_t)wsel * CDIM + o0 + srow[it]) * CDIM + scof[it];
      int cc = scof[it];
      bptr[it] = Bx + (size_t)b * PBATCH + (size_t)(cc >> 4) * (NP * 16) + (size_t)(p0 + srow[it]) * 16 + (cc & 15);
    }
  }
  auto stageA = [&](u16* ldst) {
    gload_lds16(aptr[0], ldst + tid * 8);
    gload_lds16(aptr[1], ldst + 4096 + tid * 8);
    aptr[0] += 32; aptr[1] += 32;
  };
  auto stageB = [&](u16* ldst) {
    gload_lds16(bptr[0], ldst + 8192 + tid * 8);
    gload_lds16(bptr[1], ldst + 12288 + tid * 8);
    bptr[0] += 32768; bptr[1] += 32768;
  };

  for (int i = tid; i < 256; i += 512)
    blds[i] = bias[(size_t)wselBase * CDIM + o0 + i];
  asm volatile("s_waitcnt lgkmcnt(0)" ::: "memory");

  f32x4 acc[8][4];
#pragma unroll
  for (int mi = 0; mi < 8; ++mi)
#pragma unroll
    for (int ni = 0; ni < 4; ++ni) acc[mi][ni] = (f32x4){0.f, 0.f, 0.f, 0.f};

  stageA(lds); stageB(lds);
  stageA(lds + 16384); stageB(lds + 16384);

  int cur = 0, wb = 2;
  for (int s = 0; s < NSTEP; ++s) {
    if (s + 1 < NSTEP) {
      asm volatile("s_waitcnt vmcnt(4)" ::: "memory");
    } else {
      asm volatile("s_waitcnt vmcnt(0)" ::: "memory");
    }
    __builtin_amdgcn_s_barrier();
    asm volatile("" ::: "memory");

    const u16* la = lds + cur * 16384;
    u16* ldst = lds + wb * 16384;
    const bool dostage = (s + 2) < NSTEP;

    half8 af[4], bf[4];
#pragma unroll
    for (int n = 0; n < 4; ++n) bf[n] = *(const half8*)(la + baseB + n * 512);
#pragma unroll
    for (int m = 0; m < 4; ++m) af[m] = *(const half8*)(la + baseA + m * 512);
    if (dostage) stageA(ldst);
    asm volatile("s_waitcnt lgkmcnt(0)" ::: "memory");
    __builtin_amdgcn_s_setprio(1);
#pragma unroll
    for (int m = 0; m < 4; ++m)
#pragma unroll
      for (int n = 0; n < 4; ++n)
        acc[m][n] = __builtin_amdgcn_mfma_f32_16x16x32_f16(af[m], bf[n], acc[m][n], 0, 0, 0);
    __builtin_amdgcn_s_setprio(0);

#pragma unroll
    for (int m = 0; m < 4; ++m) af[m] = *(const half8*)(la + baseA + (4 + m) * 512);
    if (dostage) stageB(ldst);
    asm volatile("s_waitcnt lgkmcnt(0)" ::: "memory");
    __builtin_amdgcn_s_setprio(1);
#pragma unroll
    for (int m = 0; m < 4; ++m)
#pragma unroll
      for (int n = 0; n < 4; ++n)
        acc[4 + m][n] = __builtin_amdgcn_mfma_f32_16x16x32_f16(af[m], bf[n], acc[4 + m][n], 0, 0, 0);
    __builtin_amdgcn_s_setprio(0);

    cur = cur == 2 ? 0 : cur + 1;
    wb = wb == 2 ? 0 : wb + 1;
  }

#pragma unroll
  for (int mi = 0; mi < 8; ++mi) {
    int rowb = o0 + wr * 128 + mi * 16 + l4 * 4;
    float4 bv = *(const float4*)&blds[wr * 128 + mi * 16 + l4 * 4];
    float bvf[4] = {bv.x, bv.y, bv.z, bv.w};
#pragma unroll
    for (int ni = 0; ni < 4; ++ni) {
      int col = p0 + wc * 64 + ni * 16 + l15;
      float* dp = dst + ((size_t)b * CDIM + rowb) * NP + col;
#pragma unroll
      for (int r = 0; r < 4; ++r)
        dp[(size_t)r * NP] = fmaxf(0.f, acc[mi][ni][r] + bvf[r]);
    }
  }
}

// ---------------- MFMA attention v3: 16 pairs/block, f16 LDS, tiled output ----------------
// LDS per pair: Q [32][32] f16 (2KB) | K [32][32] f16 (2KB); chunk-of-8 XOR: phys = c ^ akey(row).
// Staged via gload_lds (linear dest, pre-swizzled per-lane source). r11-proven MFMA/softmax math.
// P (f16) overwrites K; out (f16) overwrites Q; epilogue writes tiled aoT linearly.
__global__ __launch_bounds__(1024) void attn_t_k(const u16* __restrict__ hs, u16* __restrict__ aoT) {
  extern __shared__ u16 att[];  // 16 * 2048 u16 = 64KB
  const int tid = threadIdx.x, w = tid >> 6, lane = tid & 63;
  const int pair0 = blockIdx.x * 16;
  const int b = pair0 / CDIM;
  const int c0 = pair0 % CDIM;
  const int l15 = lane & 15, l4 = lane >> 4;

#pragma unroll
  for (int it = 0; it < 4; ++it) {
    int d = it * 1024 + tid;
    int pair = d >> 8, mat = (d >> 7) & 1, rem = d & 127;
    int r = rem >> 2, ph = rem & 3;
    int ch = ph ^ akey(r);
    const u16* src = hs + (size_t)mat * CHW + (size_t)(pair0 + pair) * NP + r * 32 + ch * 8;
    gload_lds16(src, att + (size_t)d * 8);
  }
  asm volatile("s_waitcnt vmcnt(0)" ::: "memory");
  __syncthreads();

  u16* Qb = att + w * 2048;
  u16* Kb = Qb + 1024;

  auto rd_row8 = [&](const u16* M, int row) -> half8 {
    return *(const half8*)(M + row * 32 + (l4 ^ akey(row)) * 8);
  };
  auto rd_col8 = [&](const u16* M, int col) -> half8 {
    union { u16 u[8]; half8 h; } t;
#pragma unroll
    for (int e = 0; e < 8; ++e) {
      int row = l4 * 8 + e;
      t.u[e] = M[row * 32 + ((col >> 3) ^ akey(row)) * 8 + (col & 7)];
    }
    return t.h;
  };

  // ---- S^T = mfma(A=K, B=Q): lane holds S[i=it*16+l15][j=mh*16+l4*4+r]
  half8 bq[2], akk[2];
#pragma unroll
  for (int it = 0; it < 2; ++it) bq[it] = rd_row8(Qb, it * 16 + l15);
#pragma unroll
  for (int mh = 0; mh < 2; ++mh) akk[mh] = rd_col8(Kb, mh * 16 + l15);
  f32x4 sacc[2][2];
#pragma unroll
  for (int mh = 0; mh < 2; ++mh)
#pragma unroll
    for (int it = 0; it < 2; ++it)
      sacc[mh][it] = __builtin_amdgcn_mfma_f32_16x16x32_f16(
          akk[mh], bq[it], (f32x4){0.f, 0.f, 0.f, 0.f}, 0, 0, 0);

  // ---- row softmax; P (f16) -> Kb (K dead)
#pragma unroll
  for (int it = 0; it < 2; ++it) {
    float mx = sacc[0][it][0];
#pragma unroll
    for (int r = 1; r < 4; ++r) mx = fmaxf(mx, sacc[0][it][r]);
#pragma unroll
    for (int r = 0; r < 4; ++r) mx = fmaxf(mx, sacc[1][it][r]);
    mx = fmaxf(mx, __shfl_xor(mx, 16));
    mx = fmaxf(mx, __shfl_xor(mx, 32));
    float pv[2][4];
    float sum = 0.f;
#pragma unroll
    for (int mh = 0; mh < 2; ++mh)
#pragma unroll
      for (int r = 0; r < 4; ++r) {
        pv[mh][r] = expf(sacc[mh][it][r] - mx);
        sum += pv[mh][r];
      }
    sum += __shfl_xor(sum, 16);
    sum += __shfl_xor(sum, 32);
    float inv = 1.f / sum;
    int row = it * 16 + l15;
    int rk = akey(row);
#pragma unroll
    for (int mh = 0; mh < 2; ++mh) {
      int c = mh * 16 + l4 * 4;
      uint2 wv;
      wv.x = (u32)f16bits(pv[mh][0] * inv) | ((u32)f16bits(pv[mh][1] * inv) << 16);
      wv.y = (u32)f16bits(pv[mh][2] * inv) | ((u32)f16bits(pv[mh][3] * inv) << 16);
      *(uint2*)(Kb + row * 32 + ((c >> 3) ^ rk) * 8 + (c & 7)) = wv;
    }
  }

  // ---- out = mfma(A=V(=Q), B=P): lane holds out[i=it*16+l15][h=ht*16+l4*4+r]
  half8 bp[2], av[2];
#pragma unroll
  for (int it = 0; it < 2; ++it) bp[it] = rd_row8(Kb, it * 16 + l15);
#pragma unroll
  for (int ht = 0; ht < 2; ++ht) av[ht] = rd_col8(Qb, ht * 16 + l15);
  f32x4 oacc[2][2];
#pragma unroll
  for (int ht = 0; ht < 2; ++ht)
#pragma unroll
    for (int it = 0; it < 2; ++it)
      oacc[ht][it] = __builtin_amdgcn_mfma_f32_16x16x32_f16(
          av[ht], bp[it], (f32x4){0.f, 0.f, 0.f, 0.f}, 0, 0, 0);

  // out (f16) -> Qb (V consumed)
#pragma unroll
  for (int it = 0; it < 2; ++it) {
    int row = it * 16 + l15;
    int rk = akey(row);
#pragma unroll
    for (int ht = 0; ht < 2; ++ht) {
      int c = ht * 16 + l4 * 4;
      uint2 wv;
      wv.x = (u32)f16bits(oacc[ht][it][0]) | ((u32)f16bits(oacc[ht][it][1]) << 16);
      wv.y = (u32)f16bits(oacc[ht][it][2]) | ((u32)f16bits(oacc[ht][it][3]) << 16);
      *(uint2*)(Qb + row * 32 + ((c >> 3) ^ rk) * 8 + (c & 7)) = wv;
    }
  }
  __syncthreads();

  // epilogue: aoT tiled [b][c>>4][p][c&15]; block covers exactly one c-tile -> linear stores
#pragma unroll
  for (int it = 0; it < 4; ++it) {
    int s = it * 1024 + tid;
    int p = s >> 2, cq = s & 3;
    int row = p >> 5, colh = p & 31;
    int boff = row * 32 + ((colh >> 3) ^ akey(row)) * 8 + (colh & 7);
    ushort4 v;
    v.x = att[(cq * 4 + 0) * 2048 + boff];
    v.y = att[(cq * 4 + 1) * 2048 + boff];
    v.z = att[(cq * 4 + 2) * 2048 + boff];
    v.w = att[(cq * 4 + 3) * 2048 + boff];
    *(ushort4*)&aoT[(size_t)b * PBATCH + (size_t)(c0 >> 4) * (NP * 16) + (size_t)p * 16 + cq * 4] = v;
  }
}

extern "C" void kernel_launch(void* const* d_in, const int* in_sizes, int n_in,
                              void* d_out, int out_size, void* d_ws, size_t ws_size,
                              hipStream_t stream) {
  (void)in_sizes; (void)n_in; (void)out_size; (void)ws_size;
  const float* x = (const float*)d_in[0];
  const float* Ws = (const float*)d_in[1];
  const float* bs = (const float*)d_in[2];
  float* out = (float*)d_out;
  char* ws = (char*)d_ws;

  u16* XT  = (u16*)(ws + XT_OFF);     // tiled f16
  u16* hs  = (u16*)(ws + HS_OFF);     // f16 hs11 (z0), hs111 (z1), [z][b][c][p]
  u16* Whi = (u16*)(ws + WHI_OFF);
  u16* aoT = (u16*)(ws + XT_OFF);     // tiled f16, aliases XT

  cast_w_k<<<5184, 256, 0, stream>>>(Ws, Whi);
  transpose_f16_k<<<dim3(32, 24, 32), 256, 0, stream>>>(x, XT);
  // stage-1: hs11 (z=0, W0..3) and hs111 (z=1, W4..7); 128x256 tiles, f16 out
  gemm_p<1><<<dim3(128, 6, 2), 512, 149504, stream>>>(Whi, XT, bs, (void*)hs, 4, 0, 0);
  attn_t_k<<<1536, 1024, 65536, stream>>>(hs, aoT);
  // final conv: relu(W8 @ attout + b8) -> d_out (fp32); 256x256 tiles
  gemm_r<<<dim3(128, 3, 1), 512, 99328, stream>>>(Whi, aoT, bs, out, 8);
}

// Round 14
// 444.513 us; speedup vs baseline: 1.9860x; 1.0456x over previous
//
#include <hip/hip_runtime.h>
#include <hip/hip_fp16.h>

typedef unsigned short u16;
typedef unsigned int u32;
typedef float f32x4 __attribute__((ext_vector_type(4)));
typedef _Float16 half8 __attribute__((ext_vector_type(8)));
typedef unsigned short u16x4 __attribute__((ext_vector_type(4)));

#define CDIM 768
#define NP 1024
#define NB 32

static constexpr size_t PBATCH = (size_t)CDIM * NP;   // per-batch image elems
static constexpr size_t CHW = (size_t)NB * PBATCH;    // 25,165,824

// workspace layout (bytes)
static constexpr size_t XT_OFF  = 0;                  // f16 linear [b][p][c]; reused as aoT (tiled)
static constexpr size_t HS_OFF  = CHW * 2;            // f16 hs11, hs111 ([z][b][c][p])
static constexpr size_t WHI_OFF = HS_OFF + CHW * 4;   // f16 weights

__device__ __forceinline__ u16 f16bits(float f) {
  return __half_as_ushort(__float2half_rn(f));
}
__device__ __forceinline__ float f16tof(u16 b) {
  __half_raw hr; hr.x = b; return __half2float(__half(hr));
}
__device__ __forceinline__ int akey(int r) { return ((r >> 1) & 3) ^ ((r >> 3) & 3); }

typedef __attribute__((address_space(1))) void gv_t;
typedef __attribute__((address_space(3))) void lv_t;
__device__ __forceinline__ void gload_lds16(const void* g, void* l) {
  __builtin_amdgcn_global_load_lds((gv_t*)g, (lv_t*)l, 16, 0, 0);
}

// ---------------- cast W (fp32 -> f16) ----------------
__global__ __launch_bounds__(256) void cast_w_k(const float* __restrict__ W,
                                                u16* __restrict__ hi) {
  int i = blockIdx.x * 256 + threadIdx.x;
  float4 v = ((const float4*)W)[i];
  u16x4 h4 = {f16bits(v.x), f16bits(v.y), f16bits(v.z), f16bits(v.w)};
  ((u16x4*)hi)[i] = h4;
}

// ---------------- transpose + f16 cast: fp32 [b][c][p] -> f16 linear [b][p][c] ----------------
__global__ __launch_bounds__(256) void transpose_f16_k(const float* __restrict__ src,
                                                       u16* __restrict__ dxt) {
  __shared__ float tle[32][33];
  const int b = blockIdx.z, c0 = blockIdx.y * 32, p0 = blockIdx.x * 32;
  const int tid = threadIdx.x;
  const int lr = tid >> 5, lc = tid & 31;
  const float* s = src + ((size_t)b * CDIM + c0) * NP + p0;
#pragma unroll
  for (int it = 0; it < 4; ++it) {
    int c = it * 8 + lr;
    tle[c][lc] = s[(size_t)c * NP + lc];
  }
  __syncthreads();
#pragma unroll
  for (int it = 0; it < 4; ++it) {
    int p = it * 8 + lr;
    float v = tle[lc][p];
    size_t off = ((size_t)b * NP + p0 + p) * CDIM + c0 + lc;
    dxt[off] = f16bits(v);
  }
}

// ---------------- spatial permutations ----------------
__device__ __forceinline__ int sigma_fn(int mode, int z, int t, int p) {
  if (t == 0 || mode == 1) return p;
  int i = p >> 5, j = p & 31;
  if (z == 0) {
    if (t == 1) return (j << 5) | (31 - i);
    if (t == 2) return ((31 - i) << 5) | (31 - j);
    return ((31 - j) << 5) | i;
  } else {
    int ib = i & 16, jb = j & 16, il = i & 15, jl = j & 15;
    if (t == 1) return ((ib | jl) << 5) | (jb | (15 - il));
    if (t == 2) return ((ib | (15 - il)) << 5) | (jb | (15 - jl));
    return ((ib | (15 - jl)) << 5) | (jb | il);
  }
}

// ---------------- pipelined multi-term f16 GEMM (r8/r11 config, 317us proven; B linear) ----------------
template <int OUTF16>
__global__ __launch_bounds__(512, 2) void gemm_p(
    const u16* __restrict__ Whi,
    const u16* __restrict__ Bx,
    const float* __restrict__ bias, void* __restrict__ dst,
    int nterms, int wselBase, int mode) {
  extern __shared__ u16 lds[];  // 3 x 24576 u16 + 512 f32 bias
  const int tid = threadIdx.x;
  const int lane = tid & 63;
  const int w = tid >> 6;
  const int wr = w >> 2, wc = w & 3;
  const int z = blockIdx.z;
  const int b = blockIdx.x >> 2;
  const int p0 = (blockIdx.x & 3) << 8;
  const int o0 = blockIdx.y << 7;
  const int l15 = lane & 15, l4 = lane >> 4;
  const int s7 = l15 & 7;
  float* blds = (float*)(lds + 73728);

  const int NSTEP = nterms * 12;

  const int baseA0 = (wr * 64 + l15) * 64 + ((l4) ^ s7) * 8;
  const int baseA1 = (wr * 64 + l15) * 64 + ((4 + l4) ^ s7) * 8;
  const int baseB0 = 8192 + (wc * 64 + l15) * 32 + (l4 ^ ((l15 >> 1) & 3)) * 8;
  const int baseB1 = baseB0 + 8192;

  int arow[2], acof[2];
#pragma unroll
  for (int it = 0; it < 2; ++it) {
    int d = it * 512 + tid;
    arow[it] = d >> 3;
    acof[it] = ((d & 7) ^ (arow[it] & 7)) * 8;
  }
  int brow[4], bcof[4];
#pragma unroll
  for (int it = 0; it < 4; ++it) {
    int d = it * 512 + tid;
    int h = d >> 10, rem = d & 1023;
    brow[it] = rem >> 2;
    bcof[it] = h * 32 + (((rem & 3) ^ ((brow[it] >> 1) & 3))) * 8;
  }

  const u16* aptr[2];
  const u16* bptr[4];
  auto setPtrs = [&](int term) {
    int wsel = wselBase + z * 4 + term;
#pragma unroll
    for (int it = 0; it < 2; ++it)
      aptr[it] = Whi + ((size_t)wsel * CDIM + o0 + arow[it]) * CDIM + acof[it];
#pragma unroll
    for (int it = 0; it < 4; ++it) {
      int srow = sigma_fn(mode, z, term, p0 + brow[it]);
      bptr[it] = Bx + ((size_t)b * NP + srow) * CDIM + bcof[it];
    }
  };

  if (tid < nterms * 128) {
    int t = tid >> 7, oo = tid & 127;
    blds[tid] = bias[(size_t)(wselBase + z * 4 + t) * CDIM + o0 + oo];
  }
  asm volatile("s_waitcnt lgkmcnt(0)" ::: "memory");

  f32x4 acc[4][4], racc[4][4];
#pragma unroll
  for (int m = 0; m < 4; ++m)
#pragma unroll
    for (int n = 0; n < 4; ++n) {
      acc[m][n] = (f32x4){0.f, 0.f, 0.f, 0.f};
      racc[m][n] = (f32x4){0.f, 0.f, 0.f, 0.f};
    }

  setPtrs(0);
#pragma unroll
  for (int it = 0; it < 2; ++it) gload_lds16(aptr[it], lds + (it * 512 + tid) * 8);
#pragma unroll
  for (int it = 0; it < 4; ++it) gload_lds16(bptr[it], lds + 8192 + (it * 512 + tid) * 8);
#pragma unroll
  for (int it = 0; it < 2; ++it) aptr[it] += 64;
#pragma unroll
  for (int it = 0; it < 4; ++it) bptr[it] += 64;
#pragma unroll
  for (int it = 0; it < 2; ++it) gload_lds16(aptr[it], lds + 24576 + (it * 512 + tid) * 8);
#pragma unroll
  for (int it = 0; it < 4; ++it) gload_lds16(bptr[it], lds + 24576 + 8192 + (it * 512 + tid) * 8);
#pragma unroll
  for (int it = 0; it < 2; ++it) aptr[it] += 64;
#pragma unroll
  for (int it = 0; it < 4; ++it) bptr[it] += 64;

  int nsk = 2, nst = 0;
  int ckk = 0, cterm = 0;
  int cur = 0, wb = 2;

  for (int s = 0; s < NSTEP; ++s) {
    if (s + 1 < NSTEP) {
      asm volatile("s_waitcnt vmcnt(6)" ::: "memory");
    } else {
      asm volatile("s_waitcnt vmcnt(0)" ::: "memory");
    }
    __builtin_amdgcn_s_barrier();
    asm volatile("" ::: "memory");

    const u16* la = lds + cur * 24576;
    u16* ldst = lds + wb * 24576;
    const bool dostage = (s + 2) < NSTEP;
    if (dostage && nsk == 12) { ++nst; nsk = 0; setPtrs(nst); }

    half8 ah[4], bb[4];
#pragma unroll
    for (int m = 0; m < 4; ++m) ah[m] = *(const half8*)(la + baseA0 + m * 1024);
#pragma unroll
    for (int n = 0; n < 4; ++n) bb[n] = *(const half8*)(la + baseB0 + n * 512);
    if (dostage) {
#pragma unroll
      for (int it = 0; it < 2; ++it) gload_lds16(aptr[it], ldst + (it * 512 + tid) * 8);
    }
    asm volatile("s_waitcnt lgkmcnt(0)" ::: "memory");
    __builtin_amdgcn_s_setprio(1);
#pragma unroll
    for (int m = 0; m < 4; ++m)
#pragma unroll
      for (int n = 0; n < 4; ++n)
        acc[m][n] = __builtin_amdgcn_mfma_f32_16x16x32_f16(ah[m], bb[n], acc[m][n], 0, 0, 0);
    __builtin_amdgcn_s_setprio(0);

#pragma unroll
    for (int m = 0; m < 4; ++m) ah[m] = *(const half8*)(la + baseA1 + m * 1024);
#pragma unroll
    for (int n = 0; n < 4; ++n) bb[n] = *(const half8*)(la + baseB1 + n * 512);
    if (dostage) {
#pragma unroll
      for (int it = 0; it < 4; ++it) gload_lds16(bptr[it], ldst + 8192 + (it * 512 + tid) * 8);
#pragma unroll
      for (int it = 0; it < 2; ++it) aptr[it] += 64;
#pragma unroll
      for (int it = 0; it < 4; ++it) bptr[it] += 64;
      ++nsk;
    }
    asm volatile("s_waitcnt lgkmcnt(0)" ::: "memory");
    __builtin_amdgcn_s_setprio(1);
#pragma unroll
    for (int m = 0; m < 4; ++m)
#pragma unroll
      for (int n = 0; n < 4; ++n)
        acc[m][n] = __builtin_amdgcn_mfma_f32_16x16x32_f16(ah[m], bb[n], acc[m][n], 0, 0, 0);
    __builtin_amdgcn_s_setprio(0);

    if (ckk == 11) {
#pragma unroll
      for (int m = 0; m < 4; ++m) {
        float4 bv = *(const float4*)&blds[cterm * 128 + wr * 64 + m * 16 + l4 * 4];
        float bvf[4] = {bv.x, bv.y, bv.z, bv.w};
#pragma unroll
        for (int n = 0; n < 4; ++n)
#pragma unroll
          for (int r = 0; r < 4; ++r) {
            racc[m][n][r] += fmaxf(0.f, acc[m][n][r] + bvf[r]);
            acc[m][n][r] = 0.f;
          }
      }
    }
    cur = cur == 2 ? 0 : cur + 1;
    wb = wb == 2 ? 0 : wb + 1;
    ++ckk; if (ckk == 12) { ckk = 0; ++cterm; }
  }

#pragma unroll
  for (int m = 0; m < 4; ++m) {
    int rowb = o0 + wr * 64 + m * 16 + l4 * 4;
#pragma unroll
    for (int n = 0; n < 4; ++n) {
      int col = p0 + wc * 64 + n * 16 + l15;
      size_t base = ((size_t)b * CDIM + rowb) * NP + col;
      if (OUTF16) {
        u16* dp = (u16*)dst + (size_t)z * CHW + base;
#pragma unroll
        for (int r = 0; r < 4; ++r) dp[(size_t)r * NP] = f16bits(racc[m][n][r]);
      } else {
        float* dp = (float*)dst + (size_t)z * CHW + base;
#pragma unroll
        for (int r = 0; r < 4; ++r) dp[(size_t)r * NP] = racc[m][n][r];
      }
    }
  }
}

// ---------------- 256x256-tile f16 GEMM (final conv; B tiled [b][c>>4][p][c&15]) ----------------
__global__ __launch_bounds__(512, 2) void gemm_r(
    const u16* __restrict__ Whi,
    const u16* __restrict__ Bx,
    const float* __restrict__ bias, float* __restrict__ dst,
    int wselBase) {
  extern __shared__ u16 lds[];  // 3 x 16384 u16 + 256 f32 bias
  const int tid = threadIdx.x;
  const int lane = tid & 63;
  const int w = tid >> 6;
  const int wr = w >> 2, wc = w & 3;
  const int b = blockIdx.x >> 2;
  const int p0 = (blockIdx.x & 3) << 8;
  const int o0 = blockIdx.y << 8;
  const int l15 = lane & 15, l4 = lane >> 4;
  float* blds = (float*)(lds + 49152);
  const int NSTEP = 24;

  const int rA = wr * 128 + l15;
  const int baseA = rA * 32 + (l4 ^ ((rA >> 1) & 3)) * 8;
  const int rB = wc * 64 + l15;
  const int baseB = 8192 + rB * 32 + (l4 ^ ((rB >> 1) & 3)) * 8;

  int srow[2], scof[2];
#pragma unroll
  for (int it = 0; it < 2; ++it) {
    int d = it * 512 + tid;
    srow[it] = d >> 2;
    scof[it] = ((d & 3) ^ ((srow[it] >> 1) & 3)) * 8;
  }
  const u16* aptr[2];
  const u16* bptr[2];
  {
#pragma unroll
    for (int it = 0; it < 2; ++it) {
      aptr[it] = Whi + ((size_t)wselBase * CDIM + o0 + srow[it]) * CDIM + scof[it];
      int cc = scof[it];
      bptr[it] = Bx + (size_t)b * PBATCH + (size_t)(cc >> 4) * (NP * 16) + (size_t)(p0 + srow[it]) * 16 + (cc & 15);
    }
  }
  auto stageA = [&](u16* ldst) {
    gload_lds16(aptr[0], ldst + tid * 8);
    gload_lds16(aptr[1], ldst + 4096 + tid * 8);
    aptr[0] += 32; aptr[1] += 32;
  };
  auto stageB = [&](u16* ldst) {
    gload_lds16(bptr[0], ldst + 8192 + tid * 8);
    gload_lds16(bptr[1], ldst + 12288 + tid * 8);
    bptr[0] += 32768; bptr[1] += 32768;
  };

  for (int i = tid; i < 256; i += 512)
    blds[i] = bias[(size_t)wselBase * CDIM + o0 + i];
  asm volatile("s_waitcnt lgkmcnt(0)" ::: "memory");

  f32x4 acc[8][4];
#pragma unroll
  for (int mi = 0; mi < 8; ++mi)
#pragma unroll
    for (int ni = 0; ni < 4; ++ni) acc[mi][ni] = (f32x4){0.f, 0.f, 0.f, 0.f};

  stageA(lds); stageB(lds);
  stageA(lds + 16384); stageB(lds + 16384);

  int cur = 0, wb = 2;
  for (int s = 0; s < NSTEP; ++s) {
    if (s + 1 < NSTEP) {
      asm volatile("s_waitcnt vmcnt(4)" ::: "memory");
    } else {
      asm volatile("s_waitcnt vmcnt(0)" ::: "memory");
    }
    __builtin_amdgcn_s_barrier();
    asm volatile("" ::: "memory");

    const u16* la = lds + cur * 16384;
    u16* ldst = lds + wb * 16384;
    const bool dostage = (s + 2) < NSTEP;

    half8 af[4], bf[4];
#pragma unroll
    for (int n = 0; n < 4; ++n) bf[n] = *(const half8*)(la + baseB + n * 512);
#pragma unroll
    for (int m = 0; m < 4; ++m) af[m] = *(const half8*)(la + baseA + m * 512);
    if (dostage) stageA(ldst);
    asm volatile("s_waitcnt lgkmcnt(0)" ::: "memory");
    __builtin_amdgcn_s_setprio(1);
#pragma unroll
    for (int m = 0; m < 4; ++m)
#pragma unroll
      for (int n = 0; n < 4; ++n)
        acc[m][n] = __builtin_amdgcn_mfma_f32_16x16x32_f16(af[m], bf[n], acc[m][n], 0, 0, 0);
    __builtin_amdgcn_s_setprio(0);

#pragma unroll
    for (int m = 0; m < 4; ++m) af[m] = *(const half8*)(la + baseA + (4 + m) * 512);
    if (dostage) stageB(ldst);
    asm volatile("s_waitcnt lgkmcnt(0)" ::: "memory");
    __builtin_amdgcn_s_setprio(1);
#pragma unroll
    for (int m = 0; m < 4; ++m)
#pragma unroll
      for (int n = 0; n < 4; ++n)
        acc[4 + m][n] = __builtin_amdgcn_mfma_f32_16x16x32_f16(af[m], bf[n], acc[4 + m][n], 0, 0, 0);
    __builtin_amdgcn_s_setprio(0);

    cur = cur == 2 ? 0 : cur + 1;
    wb = wb == 2 ? 0 : wb + 1;
  }

#pragma unroll
  for (int mi = 0; mi < 8; ++mi) {
    int rowb = o0 + wr * 128 + mi * 16 + l4 * 4;
    float4 bv = *(const float4*)&blds[wr * 128 + mi * 16 + l4 * 4];
    float bvf[4] = {bv.x, bv.y, bv.z, bv.w};
#pragma unroll
    for (int ni = 0; ni < 4; ++ni) {
      int col = p0 + wc * 64 + ni * 16 + l15;
      float* dp = dst + ((size_t)b * CDIM + rowb) * NP + col;
#pragma unroll
      for (int r = 0; r < 4; ++r)
        dp[(size_t)r * NP] = fmaxf(0.f, acc[mi][ni][r] + bvf[r]);
    }
  }
}

// ---------------- MFMA attention v3 (r13, proven): 16 pairs/block, f16 LDS, tiled output ----------------
__global__ __launch_bounds__(1024) void attn_t_k(const u16* __restrict__ hs, u16* __restrict__ aoT) {
  extern __shared__ u16 att[];  // 16 * 2048 u16 = 64KB
  const int tid = threadIdx.x, w = tid >> 6, lane = tid & 63;
  const int pair0 = blockIdx.x * 16;
  const int b = pair0 / CDIM;
  const int c0 = pair0 % CDIM;
  const int l15 = lane & 15, l4 = lane >> 4;

#pragma unroll
  for (int it = 0; it < 4; ++it) {
    int d = it * 1024 + tid;
    int pair = d >> 8, mat = (d >> 7) & 1, rem = d & 127;
    int r = rem >> 2, ph = rem & 3;
    int ch = ph ^ akey(r);
    const u16* src = hs + (size_t)mat * CHW + (size_t)(pair0 + pair) * NP + r * 32 + ch * 8;
    gload_lds16(src, att + (size_t)d * 8);
  }
  asm volatile("s_waitcnt vmcnt(0)" ::: "memory");
  __syncthreads();

  u16* Qb = att + w * 2048;
  u16* Kb = Qb + 1024;

  auto rd_row8 = [&](const u16* M, int row) -> half8 {
    return *(const half8*)(M + row * 32 + (l4 ^ akey(row)) * 8);
  };
  auto rd_col8 = [&](const u16* M, int col) -> half8 {
    union { u16 u[8]; half8 h; } t;
#pragma unroll
    for (int e = 0; e < 8; ++e) {
      int row = l4 * 8 + e;
      t.u[e] = M[row * 32 + ((col >> 3) ^ akey(row)) * 8 + (col & 7)];
    }
    return t.h;
  };

  half8 bq[2], akk[2];
#pragma unroll
  for (int it = 0; it < 2; ++it) bq[it] = rd_row8(Qb, it * 16 + l15);
#pragma unroll
  for (int mh = 0; mh < 2; ++mh) akk[mh] = rd_col8(Kb, mh * 16 + l15);
  f32x4 sacc[2][2];
#pragma unroll
  for (int mh = 0; mh < 2; ++mh)
#pragma unroll
    for (int it = 0; it < 2; ++it)
      sacc[mh][it] = __builtin_amdgcn_mfma_f32_16x16x32_f16(
          akk[mh], bq[it], (f32x4){0.f, 0.f, 0.f, 0.f}, 0, 0, 0);

#pragma unroll
  for (int it = 0; it < 2; ++it) {
    float mx = sacc[0][it][0];
#pragma unroll
    for (int r = 1; r < 4; ++r) mx = fmaxf(mx, sacc[0][it][r]);
#pragma unroll
    for (int r = 0; r < 4; ++r) mx = fmaxf(mx, sacc[1][it][r]);
    mx = fmaxf(mx, __shfl_xor(mx, 16));
    mx = fmaxf(mx, __shfl_xor(mx, 32));
    float pv[2][4];
    float sum = 0.f;
#pragma unroll
    for (int mh = 0; mh < 2; ++mh)
#pragma unroll
      for (int r = 0; r < 4; ++r) {
        pv[mh][r] = expf(sacc[mh][it][r] - mx);
        sum += pv[mh][r];
      }
    sum += __shfl_xor(sum, 16);
    sum += __shfl_xor(sum, 32);
    float inv = 1.f / sum;
    int row = it * 16 + l15;
    int rk = akey(row);
#pragma unroll
    for (int mh = 0; mh < 2; ++mh) {
      int c = mh * 16 + l4 * 4;
      uint2 wv;
      wv.x = (u32)f16bits(pv[mh][0] * inv) | ((u32)f16bits(pv[mh][1] * inv) << 16);
      wv.y = (u32)f16bits(pv[mh][2] * inv) | ((u32)f16bits(pv[mh][3] * inv) << 16);
      *(uint2*)(Kb + row * 32 + ((c >> 3) ^ rk) * 8 + (c & 7)) = wv;
    }
  }

  half8 bp[2], av[2];
#pragma unroll
  for (int it = 0; it < 2; ++it) bp[it] = rd_row8(Kb, it * 16 + l15);
#pragma unroll
  for (int ht = 0; ht < 2; ++ht) av[ht] = rd_col8(Qb, ht * 16 + l15);
  f32x4 oacc[2][2];
#pragma unroll
  for (int ht = 0; ht < 2; ++ht)
#pragma unroll
    for (int it = 0; it < 2; ++it)
      oacc[ht][it] = __builtin_amdgcn_mfma_f32_16x16x32_f16(
          av[ht], bp[it], (f32x4){0.f, 0.f, 0.f, 0.f}, 0, 0, 0);

#pragma unroll
  for (int it = 0; it < 2; ++it) {
    int row = it * 16 + l15;
    int rk = akey(row);
#pragma unroll
    for (int ht = 0; ht < 2; ++ht) {
      int c = ht * 16 + l4 * 4;
      uint2 wv;
      wv.x = (u32)f16bits(oacc[ht][it][0]) | ((u32)f16bits(oacc[ht][it][1]) << 16);
      wv.y = (u32)f16bits(oacc[ht][it][2]) | ((u32)f16bits(oacc[ht][it][3]) << 16);
      *(uint2*)(Qb + row * 32 + ((c >> 3) ^ rk) * 8 + (c & 7)) = wv;
    }
  }
  __syncthreads();

  // epilogue: aoT tiled [b][c>>4][p][c&15]; block covers exactly one c-tile -> linear stores
#pragma unroll
  for (int it = 0; it < 4; ++it) {
    int s = it * 1024 + tid;
    int p = s >> 2, cq = s & 3;
    int row = p >> 5, colh = p & 31;
    int boff = row * 32 + ((colh >> 3) ^ akey(row)) * 8 + (colh & 7);
    ushort4 v;
    v.x = att[(cq * 4 + 0) * 2048 + boff];
    v.y = att[(cq * 4 + 1) * 2048 + boff];
    v.z = att[(cq * 4 + 2) * 2048 + boff];
    v.w = att[(cq * 4 + 3) * 2048 + boff];
    *(ushort4*)&aoT[(size_t)b * PBATCH + (size_t)(c0 >> 4) * (NP * 16) + (size_t)p * 16 + cq * 4] = v;
  }
}

extern "C" void kernel_launch(void* const* d_in, const int* in_sizes, int n_in,
                              void* d_out, int out_size, void* d_ws, size_t ws_size,
                              hipStream_t stream) {
  (void)in_sizes; (void)n_in; (void)out_size; (void)ws_size;
  const float* x = (const float*)d_in[0];
  const float* Ws = (const float*)d_in[1];
  const float* bs = (const float*)d_in[2];
  float* out = (float*)d_out;
  char* ws = (char*)d_ws;

  u16* XT  = (u16*)(ws + XT_OFF);     // linear f16 [b][p][c]
  u16* hs  = (u16*)(ws + HS_OFF);     // f16 hs11 (z0), hs111 (z1), [z][b][c][p]
  u16* Whi = (u16*)(ws + WHI_OFF);
  u16* aoT = (u16*)(ws + XT_OFF);     // tiled f16 [b][c>>4][p][c&15], aliases XT (dead)

  cast_w_k<<<5184, 256, 0, stream>>>(Ws, Whi);
  transpose_f16_k<<<dim3(32, 24, 32), 256, 0, stream>>>(x, XT);
  // stage-1: hs11 (z=0, W0..3) and hs111 (z=1, W4..7); 128x256 tiles, linear B, f16 out
  gemm_p<1><<<dim3(128, 6, 2), 512, 149504, stream>>>(Whi, XT, bs, (void*)hs, 4, 0, 0);
  attn_t_k<<<1536, 1024, 65536, stream>>>(hs, aoT);
  // final conv: relu(W8 @ attout + b8) -> d_out (fp32); 256x256 tiles, tiled B
  gemm_r<<<dim3(128, 3, 1), 512, 99328, stream>>>(Whi, aoT, bs, out, 8);
}

// Round 15
// 443.614 us; speedup vs baseline: 1.9900x; 1.0020x over previous
//
#include <hip/hip_runtime.h>
#include <hip/hip_fp16.h>

typedef unsigned short u16;
typedef unsigned int u32;
typedef float f32x4 __attribute__((ext_vector_type(4)));
typedef _Float16 half8 __attribute__((ext_vector_type(8)));
typedef unsigned short u16x4 __attribute__((ext_vector_type(4)));

#define CDIM 768
#define NP 1024
#define NB 32

static constexpr size_t PBATCH = (size_t)CDIM * NP;
static constexpr size_t CHW = (size_t)NB * PBATCH;   // 25,165,824

// workspace layout (bytes)
static constexpr size_t XT_OFF  = 0;                  // f16 linear [b][p][c]; reused as aoT (tiled)
static constexpr size_t HS_OFF  = CHW * 2;            // f16 hs11, hs111 ([z][b][c][p])
static constexpr size_t WHI_OFF = HS_OFF + CHW * 4;   // f16 weights

__device__ __forceinline__ u16 f16bits(float f) {
  return __half_as_ushort(__float2half_rn(f));
}
__device__ __forceinline__ float f16tof(u16 b) {
  __half_raw hr; hr.x = b; return __half2float(__half(hr));
}
__device__ __forceinline__ int akey(int r) { return ((r >> 1) & 3) ^ ((r >> 3) & 3); }
__device__ __forceinline__ u32 pk2(u32 p, float a, float b) {
  float x = f16tof((u16)(p & 0xffff)) + a;
  float y = f16tof((u16)(p >> 16)) + b;
  return (u32)f16bits(x) | ((u32)f16bits(y) << 16);
}

typedef __attribute__((address_space(1))) void gv_t;
typedef __attribute__((address_space(3))) void lv_t;
__device__ __forceinline__ void gload_lds16(const void* g, void* l) {
  __builtin_amdgcn_global_load_lds((gv_t*)g, (lv_t*)l, 16, 0, 0);
}

// ---------------- cast W (fp32 -> f16) ----------------
__global__ __launch_bounds__(256) void cast_w_k(const float* __restrict__ W,
                                                u16* __restrict__ hi) {
  int i = blockIdx.x * 256 + threadIdx.x;
  float4 v = ((const float4*)W)[i];
  u16x4 h4 = {f16bits(v.x), f16bits(v.y), f16bits(v.z), f16bits(v.w)};
  ((u16x4*)hi)[i] = h4;
}

// ---------------- transpose + f16 cast: fp32 [b][c][p] -> f16 linear [b][p][c] ----------------
__global__ __launch_bounds__(256) void transpose_f16_k(const float* __restrict__ src,
                                                       u16* __restrict__ dxt) {
  __shared__ float tle[32][33];
  const int b = blockIdx.z, c0 = blockIdx.y * 32, p0 = blockIdx.x * 32;
  const int tid = threadIdx.x;
  const int lr = tid >> 5, lc = tid & 31;
  const float* s = src + ((size_t)b * CDIM + c0) * NP + p0;
#pragma unroll
  for (int it = 0; it < 4; ++it) {
    int c = it * 8 + lr;
    tle[c][lc] = s[(size_t)c * NP + lc];
  }
  __syncthreads();
#pragma unroll
  for (int it = 0; it < 4; ++it) {
    int p = it * 8 + lr;
    float v = tle[lc][p];
    size_t off = ((size_t)b * NP + p0 + p) * CDIM + c0 + lc;
    dxt[off] = f16bits(v);
  }
}

// ---------------- spatial permutations ----------------
__device__ __forceinline__ int sigma_fn(int mode, int z, int t, int p) {
  if (t == 0 || mode == 1) return p;
  int i = p >> 5, j = p & 31;
  if (z == 0) {
    if (t == 1) return (j << 5) | (31 - i);
    if (t == 2) return ((31 - i) << 5) | (31 - j);
    return ((31 - j) << 5) | i;
  } else {
    int ib = i & 16, jb = j & 16, il = i & 15, jl = j & 15;
    if (t == 1) return ((ib | jl) << 5) | (jb | (15 - il));
    if (t == 2) return ((ib | (15 - il)) << 5) | (jb | (15 - jl));
    return ((ib | (15 - jl)) << 5) | (jb | il);
  }
}

// ---------------- 256x256-tile multi-term f16 GEMM, 4-phase barrier-paired schedule ----------------
// 512 threads = 8 waves (2M x 4N), wave tile 128x64, BK=32.
// 3 LDS buffers x 32KB (A [256 rows][4 chunks of 8 u16], phys = logical ^ ((row>>1)&3);
// B identical at +8192). Buffer rotation read s%3 / stage (s+2)%3 -> regions always disjoint.
// Per step: vmcnt(4)+barrier, then 4 phases:
//   ph q: {2 A ds_read (+4 B at q=0); issue 1 gload_lds; barrier; lgkm0; setprio1; 8 MFMA; setprio0}
// vmcnt never drains to 0 mid-loop. NTERMS>1: packed-f16 racc fold at term boundary.
template <int OUTF16, int NTERMS, int TILEDB>
__global__ __launch_bounds__(512, 2) void gemm_q8(
    const u16* __restrict__ Whi,
    const u16* __restrict__ Bx,
    const float* __restrict__ bias, void* __restrict__ dst,
    int wselBase, int mode) {
  extern __shared__ u16 lds[];  // 3 x 16384 u16 + NTERMS*256 f32 bias
  const int tid = threadIdx.x;
  const int lane = tid & 63;
  const int w = tid >> 6;
  const int wr = w >> 2, wc = w & 3;
  const int z = blockIdx.z;
  const int b = blockIdx.x >> 2;
  const int p0 = (blockIdx.x & 3) << 8;
  const int o0 = blockIdx.y << 8;
  const int l15 = lane & 15, l4 = lane >> 4;
  float* blds = (float*)(lds + 49152);
  const int NSTEP = NTERMS * 24;

  // LDS read bases (u16); A frag m: +m*512 (16 rows x 32 u16), B frag n: +n*512
  const int rA = wr * 128 + l15;
  const int baseA = rA * 32 + (l4 ^ ((rA >> 1) & 3)) * 8;
  const int rB = wc * 64 + l15;
  const int baseB = 8192 + rB * 32 + (l4 ^ ((rB >> 1) & 3)) * 8;

  // staging decode: slot d = it*512+tid -> row d>>2 (0..255), phys chunk d&3,
  // logical = phys ^ ((row>>1)&3); dest linear d*16B
  int srow[2], scof[2];
#pragma unroll
  for (int it = 0; it < 2; ++it) {
    int d = it * 512 + tid;
    srow[it] = d >> 2;
    scof[it] = ((d & 3) ^ ((srow[it] >> 1) & 3)) * 8;
  }
  const u16* aptr[2];
  const u16* bptr[2];
  auto setPtrs = [&](int term) {
    int wsel = wselBase + z * 4 + term;
#pragma unroll
    for (int it = 0; it < 2; ++it) {
      aptr[it] = Whi + ((size_t)wsel * CDIM + o0 + srow[it]) * CDIM + scof[it];
      if (TILEDB) {
        int cc = scof[it];
        bptr[it] = Bx + (size_t)b * PBATCH + (size_t)(cc >> 4) * (NP * 16) +
                   (size_t)(p0 + srow[it]) * 16 + (cc & 15);
      } else {
        int srw = sigma_fn(mode, z, term, p0 + srow[it]);
        bptr[it] = Bx + ((size_t)b * NP + srw) * CDIM + scof[it];
      }
    }
  };
  auto advPtrs = [&]() {
    aptr[0] += 32; aptr[1] += 32;
    if (TILEDB) { bptr[0] += 32768; bptr[1] += 32768; }
    else { bptr[0] += 32; bptr[1] += 32; }
  };

  // bias -> LDS
  for (int i = tid; i < NTERMS * 256; i += 512)
    blds[i] = bias[(size_t)(wselBase + z * 4 + (i >> 8)) * CDIM + o0 + (i & 255)];
  asm volatile("s_waitcnt lgkmcnt(0)" ::: "memory");

  f32x4 acc[8][4];
#pragma unroll
  for (int mi = 0; mi < 8; ++mi)
#pragma unroll
    for (int ni = 0; ni < 4; ++ni) acc[mi][ni] = (f32x4){0.f, 0.f, 0.f, 0.f};
  u32 rp[8][4][2];
  if (NTERMS > 1) {
#pragma unroll
    for (int mi = 0; mi < 8; ++mi)
#pragma unroll
      for (int ni = 0; ni < 4; ++ni) { rp[mi][ni][0] = 0u; rp[mi][ni][1] = 0u; }
  }

  // prologue: stage steps 0,1 into bufs 0,1 (4 loads each, issue order A0,A1,B0,B1)
  setPtrs(0);
  gload_lds16(aptr[0], lds + tid * 8);
  gload_lds16(aptr[1], lds + 4096 + tid * 8);
  gload_lds16(bptr[0], lds + 8192 + tid * 8);
  gload_lds16(bptr[1], lds + 12288 + tid * 8);
  advPtrs();
  gload_lds16(aptr[0], lds + 16384 + tid * 8);
  gload_lds16(aptr[1], lds + 16384 + 4096 + tid * 8);
  gload_lds16(bptr[0], lds + 16384 + 8192 + tid * 8);
  gload_lds16(bptr[1], lds + 16384 + 12288 + tid * 8);
  advPtrs();

  int nsk = 2, nst = 0;   // staged steps in current term / its term
  int ckk = 0, cterm = 0; // consumed k-step / term
  int cur = 0, wb = 2;

  for (int s = 0; s < NSTEP; ++s) {
    if (s + 1 < NSTEP) {
      asm volatile("s_waitcnt vmcnt(4)" ::: "memory");
    } else {
      asm volatile("s_waitcnt vmcnt(0)" ::: "memory");
    }
    __builtin_amdgcn_s_barrier();
    asm volatile("" ::: "memory");

    const u16* la = lds + cur * 16384;
    u16* ldst = lds + wb * 16384;
    const bool dostage = (s + 2) < NSTEP;
    if (NTERMS > 1 && dostage && nsk == 24) { ++nst; nsk = 0; setPtrs(nst); }

    half8 bf[4], af[2];
    // ======== phase 0: B all + A m0-1; issue gload A[0]; 8 MFMA ========
#pragma unroll
    for (int n = 0; n < 4; ++n) bf[n] = *(const half8*)(la + baseB + n * 512);
    af[0] = *(const half8*)(la + baseA);
    af[1] = *(const half8*)(la + baseA + 512);
    if (dostage) gload_lds16(aptr[0], ldst + tid * 8);
    __builtin_amdgcn_s_barrier();
    asm volatile("s_waitcnt lgkmcnt(0)" ::: "memory");
    __builtin_amdgcn_s_setprio(1);
#pragma unroll
    for (int n = 0; n < 4; ++n) {
      acc[0][n] = __builtin_amdgcn_mfma_f32_16x16x32_f16(af[0], bf[n], acc[0][n], 0, 0, 0);
      acc[1][n] = __builtin_amdgcn_mfma_f32_16x16x32_f16(af[1], bf[n], acc[1][n], 0, 0, 0);
    }
    __builtin_amdgcn_s_setprio(0);

    // ======== phase 1: A m2-3; issue gload A[1]; 8 MFMA ========
    af[0] = *(const half8*)(la + baseA + 2 * 512);
    af[1] = *(const half8*)(la + baseA + 3 * 512);
    if (dostage) gload_lds16(aptr[1], ldst + 4096 + tid * 8);
    __builtin_amdgcn_s_barrier();
    asm volatile("s_waitcnt lgkmcnt(0)" ::: "memory");
    __builtin_amdgcn_s_setprio(1);
#pragma unroll
    for (int n = 0; n < 4; ++n) {
      acc[2][n] = __builtin_amdgcn_mfma_f32_16x16x32_f16(af[0], bf[n], acc[2][n], 0, 0, 0);
      acc[3][n] = __builtin_amdgcn_mfma_f32_16x16x32_f16(af[1], bf[n], acc[3][n], 0, 0, 0);
    }
    __builtin_amdgcn_s_setprio(0);

    // ======== phase 2: A m4-5; issue gload B[0]; 8 MFMA ========
    af[0] = *(const half8*)(la + baseA + 4 * 512);
    af[1] = *(const half8*)(la + baseA + 5 * 512);
    if (dostage) gload_lds16(bptr[0], ldst + 8192 + tid * 8);
    __builtin_amdgcn_s_barrier();
    asm volatile("s_waitcnt lgkmcnt(0)" ::: "memory");
    __builtin_amdgcn_s_setprio(1);
#pragma unroll
    for (int n = 0; n < 4; ++n) {
      acc[4][n] = __builtin_amdgcn_mfma_f32_16x16x32_f16(af[0], bf[n], acc[4][n], 0, 0, 0);
      acc[5][n] = __builtin_amdgcn_mfma_f32_16x16x32_f16(af[1], bf[n], acc[5][n], 0, 0, 0);
    }
    __builtin_amdgcn_s_setprio(0);

    // ======== phase 3: A m6-7; issue gload B[1]; 8 MFMA ========
    af[0] = *(const half8*)(la + baseA + 6 * 512);
    af[1] = *(const half8*)(la + baseA + 7 * 512);
    if (dostage) {
      gload_lds16(bptr[1], ldst + 12288 + tid * 8);
      advPtrs();
      ++nsk;
    }
    __builtin_amdgcn_s_barrier();
    asm volatile("s_waitcnt lgkmcnt(0)" ::: "memory");
    __builtin_amdgcn_s_setprio(1);
#pragma unroll
    for (int n = 0; n < 4; ++n) {
      acc[6][n] = __builtin_amdgcn_mfma_f32_16x16x32_f16(af[0], bf[n], acc[6][n], 0, 0, 0);
      acc[7][n] = __builtin_amdgcn_mfma_f32_16x16x32_f16(af[1], bf[n], acc[7][n], 0, 0, 0);
    }
    __builtin_amdgcn_s_setprio(0);

    if (NTERMS > 1 && ckk == 23) {  // term boundary: relu(acc+bias) -> packed racc
#pragma unroll
      for (int mi = 0; mi < 8; ++mi) {
        float4 bv = *(const float4*)&blds[cterm * 256 + wr * 128 + mi * 16 + l4 * 4];
#pragma unroll
        for (int ni = 0; ni < 4; ++ni) {
          rp[mi][ni][0] = pk2(rp[mi][ni][0], fmaxf(0.f, acc[mi][ni][0] + bv.x),
                                             fmaxf(0.f, acc[mi][ni][1] + bv.y));
          rp[mi][ni][1] = pk2(rp[mi][ni][1], fmaxf(0.f, acc[mi][ni][2] + bv.z),
                                             fmaxf(0.f, acc[mi][ni][3] + bv.w));
          acc[mi][ni] = (f32x4){0.f, 0.f, 0.f, 0.f};
        }
      }
    }
    cur = cur == 2 ? 0 : cur + 1;
    wb = wb == 2 ? 0 : wb + 1;
    ++ckk; if (ckk == 24) { ckk = 0; ++cterm; }
  }

  // epilogue: row = o0+wr*128+mi*16+l4*4+r, col = p0+wc*64+ni*16+l15
#pragma unroll
  for (int mi = 0; mi < 8; ++mi) {
    int rowb = o0 + wr * 128 + mi * 16 + l4 * 4;
#pragma unroll
    for (int ni = 0; ni < 4; ++ni) {
      int col = p0 + wc * 64 + ni * 16 + l15;
      size_t base = ((size_t)b * CDIM + rowb) * NP + col;
      if (NTERMS > 1) {
        u16* dp = (u16*)dst + (size_t)z * CHW + base;
        dp[0 * NP] = (u16)(rp[mi][ni][0] & 0xffff);
        dp[1 * NP] = (u16)(rp[mi][ni][0] >> 16);
        dp[2 * NP] = (u16)(rp[mi][ni][1] & 0xffff);
        dp[3 * NP] = (u16)(rp[mi][ni][1] >> 16);
      } else {
        float4 bv = *(const float4*)&blds[wr * 128 + mi * 16 + l4 * 4];
        float bvf[4] = {bv.x, bv.y, bv.z, bv.w};
        float* dp = (float*)dst + (size_t)z * CHW + base;
#pragma unroll
        for (int r = 0; r < 4; ++r)
          dp[(size_t)r * NP] = fmaxf(0.f, acc[mi][ni][r] + bvf[r]);
      }
    }
  }
}

// ---------------- MFMA attention v3 (r13/r14, proven): 16 pairs/block, f16 LDS, tiled output ----------------
__global__ __launch_bounds__(1024) void attn_t_k(const u16* __restrict__ hs, u16* __restrict__ aoT) {
  extern __shared__ u16 att[];  // 16 * 2048 u16 = 64KB
  const int tid = threadIdx.x, w = tid >> 6, lane = tid & 63;
  const int pair0 = blockIdx.x * 16;
  const int b = pair0 / CDIM;
  const int c0 = pair0 % CDIM;
  const int l15 = lane & 15, l4 = lane >> 4;

#pragma unroll
  for (int it = 0; it < 4; ++it) {
    int d = it * 1024 + tid;
    int pair = d >> 8, mat = (d >> 7) & 1, rem = d & 127;
    int r = rem >> 2, ph = rem & 3;
    int ch = ph ^ akey(r);
    const u16* src = hs + (size_t)mat * CHW + (size_t)(pair0 + pair) * NP + r * 32 + ch * 8;
    gload_lds16(src, att + (size_t)d * 8);
  }
  asm volatile("s_waitcnt vmcnt(0)" ::: "memory");
  __syncthreads();

  u16* Qb = att + w * 2048;
  u16* Kb = Qb + 1024;

  auto rd_row8 = [&](const u16* M, int row) -> half8 {
    return *(const half8*)(M + row * 32 + (l4 ^ akey(row)) * 8);
  };
  auto rd_col8 = [&](const u16* M, int col) -> half8 {
    union { u16 u[8]; half8 h; } t;
#pragma unroll
    for (int e = 0; e < 8; ++e) {
      int row = l4 * 8 + e;
      t.u[e] = M[row * 32 + ((col >> 3) ^ akey(row)) * 8 + (col & 7)];
    }
    return t.h;
  };

  half8 bq[2], akk[2];
#pragma unroll
  for (int it = 0; it < 2; ++it) bq[it] = rd_row8(Qb, it * 16 + l15);
#pragma unroll
  for (int mh = 0; mh < 2; ++mh) akk[mh] = rd_col8(Kb, mh * 16 + l15);
  f32x4 sacc[2][2];
#pragma unroll
  for (int mh = 0; mh < 2; ++mh)
#pragma unroll
    for (int it = 0; it < 2; ++it)
      sacc[mh][it] = __builtin_amdgcn_mfma_f32_16x16x32_f16(
          akk[mh], bq[it], (f32x4){0.f, 0.f, 0.f, 0.f}, 0, 0, 0);

#pragma unroll
  for (int it = 0; it < 2; ++it) {
    float mx = sacc[0][it][0];
#pragma unroll
    for (int r = 1; r < 4; ++r) mx = fmaxf(mx, sacc[0][it][r]);
#pragma unroll
    for (int r = 0; r < 4; ++r) mx = fmaxf(mx, sacc[1][it][r]);
    mx = fmaxf(mx, __shfl_xor(mx, 16));
    mx = fmaxf(mx, __shfl_xor(mx, 32));
    float pv[2][4];
    float sum = 0.f;
#pragma unroll
    for (int mh = 0; mh < 2; ++mh)
#pragma unroll
      for (int r = 0; r < 4; ++r) {
        pv[mh][r] = expf(sacc[mh][it][r] - mx);
        sum += pv[mh][r];
      }
    sum += __shfl_xor(sum, 16);
    sum += __shfl_xor(sum, 32);
    float inv = 1.f / sum;
    int row = it * 16 + l15;
    int rk = akey(row);
#pragma unroll
    for (int mh = 0; mh < 2; ++mh) {
      int c = mh * 16 + l4 * 4;
      uint2 wv;
      wv.x = (u32)f16bits(pv[mh][0] * inv) | ((u32)f16bits(pv[mh][1] * inv) << 16);
      wv.y = (u32)f16bits(pv[mh][2] * inv) | ((u32)f16bits(pv[mh][3] * inv) << 16);
      *(uint2*)(Kb + row * 32 + ((c >> 3) ^ rk) * 8 + (c & 7)) = wv;
    }
  }

  half8 bp[2], av[2];
#pragma unroll
  for (int it = 0; it < 2; ++it) bp[it] = rd_row8(Kb, it * 16 + l15);
#pragma unroll
  for (int ht = 0; ht < 2; ++ht) av[ht] = rd_col8(Qb, ht * 16 + l15);
  f32x4 oacc[2][2];
#pragma unroll
  for (int ht = 0; ht < 2; ++ht)
#pragma unroll
    for (int it = 0; it < 2; ++it)
      oacc[ht][it] = __builtin_amdgcn_mfma_f32_16x16x32_f16(
          av[ht], bp[it], (f32x4){0.f, 0.f, 0.f, 0.f}, 0, 0, 0);

#pragma unroll
  for (int it = 0; it < 2; ++it) {
    int row = it * 16 + l15;
    int rk = akey(row);
#pragma unroll
    for (int ht = 0; ht < 2; ++ht) {
      int c = ht * 16 + l4 * 4;
      uint2 wv;
      wv.x = (u32)f16bits(oacc[ht][it][0]) | ((u32)f16bits(oacc[ht][it][1]) << 16);
      wv.y = (u32)f16bits(oacc[ht][it][2]) | ((u32)f16bits(oacc[ht][it][3]) << 16);
      *(uint2*)(Qb + row * 32 + ((c >> 3) ^ rk) * 8 + (c & 7)) = wv;
    }
  }
  __syncthreads();

#pragma unroll
  for (int it = 0; it < 4; ++it) {
    int s = it * 1024 + tid;
    int p = s >> 2, cq = s & 3;
    int row = p >> 5, colh = p & 31;
    int boff = row * 32 + ((colh >> 3) ^ akey(row)) * 8 + (colh & 7);
    ushort4 v;
    v.x = att[(cq * 4 + 0) * 2048 + boff];
    v.y = att[(cq * 4 + 1) * 2048 + boff];
    v.z = att[(cq * 4 + 2) * 2048 + boff];
    v.w = att[(cq * 4 + 3) * 2048 + boff];
    *(ushort4*)&aoT[(size_t)b * PBATCH + (size_t)(c0 >> 4) * (NP * 16) + (size_t)p * 16 + cq * 4] = v;
  }
}

extern "C" void kernel_launch(void* const* d_in, const int* in_sizes, int n_in,
                              void* d_out, int out_size, void* d_ws, size_t ws_size,
                              hipStream_t stream) {
  (void)in_sizes; (void)n_in; (void)out_size; (void)ws_size;
  const float* x = (const float*)d_in[0];
  const float* Ws = (const float*)d_in[1];
  const float* bs = (const float*)d_in[2];
  float* out = (float*)d_out;
  char* ws = (char*)d_ws;

  u16* XT  = (u16*)(ws + XT_OFF);     // linear f16 [b][p][c]
  u16* hs  = (u16*)(ws + HS_OFF);     // f16 hs11 (z0), hs111 (z1)
  u16* Whi = (u16*)(ws + WHI_OFF);
  u16* aoT = (u16*)(ws + XT_OFF);     // tiled f16 [b][c>>4][p][c&15], aliases XT (dead)

  cast_w_k<<<5184, 256, 0, stream>>>(Ws, Whi);
  transpose_f16_k<<<dim3(32, 24, 32), 256, 0, stream>>>(x, XT);
  // stage-1: hs11 (z=0, W0..3) and hs111 (z=1, W4..7); 256x256 tiles, linear B, f16 out
  gemm_q8<1, 4, 0><<<dim3(128, 3, 2), 512, 102400, stream>>>(Whi, XT, bs, (void*)hs, 0, 0);
  attn_t_k<<<1536, 1024, 65536, stream>>>(hs, aoT);
  // final conv: relu(W8 @ attout + b8) -> d_out (fp32); 256x256 tiles, tiled B
  gemm_q8<0, 1, 1><<<dim3(128, 3, 1), 512, 99328, stream>>>(Whi, aoT, bs, (void*)out, 8, 1);
}